// Round 2
// baseline (8982.851 us; speedup 1.0000x reference)
//
#include <hip/hip_runtime.h>
#include <hip/hip_bf16.h>

#define NV 50000
#define NL 100000
#define NC 210000
#define NNZE 630000
#define F 80

#define BM 64
#define BN 64
#define BKK 16

// ---------------- offsets from sorted edge_clause ----------------
__global__ void build_off(const int* __restrict__ ec, int* __restrict__ off,
                          int nnz, int nc) {
    int e = blockIdx.x * 256 + threadIdx.x;
    if (e >= nnz) return;
    int c = ec[e];
    if (e == 0) {
        for (int cc = 0; cc <= c; ++cc) off[cc] = 0;
    } else {
        int cp = ec[e - 1];
        for (int cc = cp + 1; cc <= c; ++cc) off[cc] = e;
    }
    if (e == nnz - 1) {
        for (int cc = c + 1; cc <= nc; ++cc) off[cc] = nnz;
    }
}

// ---------------- fills ----------------
__global__ void fill_val(float* __restrict__ p, int n, const float* __restrict__ v) {
    int i = blockIdx.x * 256 + threadIdx.x;
    if (i < n) p[i] = v[0];
}

__global__ void zero_fill(float* __restrict__ p, int n) {
    int i = blockIdx.x * 256 + threadIdx.x;
    if (i < n) p[i] = 0.f;
}

// ---------------- LC gather: per (clause, feature) ----------------
__global__ void lc_gather(const float* __restrict__ L, const int* __restrict__ el,
                          const int* __restrict__ off, const float* __restrict__ scale,
                          float* __restrict__ LC) {
    int idx = blockIdx.x * 256 + threadIdx.x;
    if (idx >= NC * F) return;
    int c = idx / F, f = idx % F;
    int e0 = off[c], e1 = off[c + 1];
    float s = 0.f;
    for (int e = e0; e < e1; ++e)
        s += L[(size_t)el[e] * F + f];
    LC[idx] = s * scale[0];
}

// ---------------- CL scatter: per (edge, feature), atomics ----------------
__global__ void cl_scatter(const float* __restrict__ C, const int* __restrict__ el,
                           const int* __restrict__ ec, const float* __restrict__ scale,
                           float* __restrict__ CL) {
    int idx = blockIdx.x * 256 + threadIdx.x;
    if (idx >= NNZE * F) return;
    int e = idx / F, f = idx % F;
    float v = C[(size_t)ec[e] * F + f] * scale[0];
    atomicAdd(&CL[(size_t)el[e] * F + f], v);
}

// ---------------- fused piecewise GEMM: Out = act(A @ W + b) ----------------
// A is up to 3 row-major pieces of width pw each (K = pw * npieces).
// Pieces 0/1 are indexed by LOCAL row (pre-offset pointers for chunking).
// Piece 2 with flip2 uses global row = rbase + local, flipped (L_flip).
__global__ __launch_bounds__(256)
void gemm_fused(const float* __restrict__ A0, const float* __restrict__ A1,
                const float* __restrict__ A2, int pw, int flip2, int rbase,
                int M, int K, int N,
                const float* __restrict__ W, const float* __restrict__ bias,
                float* __restrict__ Out, int act) {
    __shared__ float As[BKK][BM + 4];
    __shared__ float Bs[BKK][BN + 4];
    int m0 = blockIdx.x * BM, n0 = blockIdx.y * BN;
    int tid = threadIdx.x;
    int tx = tid % 16, ty = tid / 16;
    float acc[4][4] = {};

    for (int k0 = 0; k0 < K; k0 += BKK) {
        {   // A tile: 64 rows x 16 k
            int lk = tid % 16, lm = tid / 16;
            int kg = k0 + lk;
            int piece = kg / pw, kk = kg - piece * pw;
#pragma unroll
            for (int i = 0; i < 4; ++i) {
                int m = lm + i * 16;
                int row = m0 + m;
                float v = 0.f;
                if (row < M) {
                    const float* P;
                    int re = row;
                    if (piece == 0) P = A0;
                    else if (piece == 1) P = A1;
                    else {
                        P = A2;
                        if (flip2) {
                            int g = rbase + row;
                            re = (g < NV) ? g + NV : g - NV;
                        }
                    }
                    v = P[(size_t)re * pw + kk];
                }
                As[lk][m] = v;
            }
        }
        {   // W tile: 16 k x 64 n
            int ln = tid % 64, lk = tid / 64;
#pragma unroll
            for (int i = 0; i < 4; ++i) {
                int k = lk + i * 4;
                int n = n0 + ln;
                Bs[k][ln] = (n < N) ? W[(size_t)(k0 + k) * N + n] : 0.f;
            }
        }
        __syncthreads();
#pragma unroll
        for (int kk = 0; kk < BKK; ++kk) {
            float a[4], b[4];
#pragma unroll
            for (int i = 0; i < 4; ++i) a[i] = As[kk][ty * 4 + i];
#pragma unroll
            for (int j = 0; j < 4; ++j) b[j] = Bs[kk][tx * 4 + j];
#pragma unroll
            for (int i = 0; i < 4; ++i)
#pragma unroll
                for (int j = 0; j < 4; ++j) acc[i][j] += a[i] * b[j];
        }
        __syncthreads();
    }
#pragma unroll
    for (int i = 0; i < 4; ++i) {
        int row = m0 + ty * 4 + i;
        if (row >= M) continue;
#pragma unroll
        for (int j = 0; j < 4; ++j) {
            int col = n0 + tx * 4 + j;
            if (col >= N) continue;
            float v = acc[i][j] + bias[col];
            if (act) v = fminf(fmaxf(v, 0.f), 6.f);
            Out[(size_t)row * N + col] = v;
        }
    }
}

// ---------------- column stats (mean/var over axis 0), 2-stage deterministic ----
__global__ __launch_bounds__(256)
void colstats_partial(const float* __restrict__ X, int M,
                      float* __restrict__ Psum, float* __restrict__ Psq) {
    __shared__ float sd[256], qd[256];
    int tid = threadIdx.x;
    int col = tid % 80;
    int slot = tid / 80;     // 0..3 (slot 3 inactive)
    int base = blockIdx.x * 96;
    float s = 0.f, q = 0.f;
    if (slot < 3) {
        for (int i = 0; i < 32; ++i) {
            int r = base + slot + i * 3;
            if (r < M) {
                float v = X[(size_t)r * F + col];
                s += v; q += v * v;
            }
        }
    }
    sd[tid] = s; qd[tid] = q;
    __syncthreads();
    if (tid < 80) {
        float ts = sd[tid] + sd[tid + 80] + sd[tid + 160];
        float tq = qd[tid] + qd[tid + 80] + qd[tid + 160];
        Psum[(size_t)blockIdx.x * 80 + tid] = ts;
        Psq [(size_t)blockIdx.x * 80 + tid] = tq;
    }
}

__global__ void colstats_final(const float* __restrict__ Psum, const float* __restrict__ Psq,
                               int nblk, int M, float* __restrict__ stats) {
    int c = threadIdx.x;
    if (c >= 80) return;
    float s = 0.f, q = 0.f;
    for (int b = 0; b < nblk; ++b) { s += Psum[(size_t)b * 80 + c]; q += Psq[(size_t)b * 80 + c]; }
    float mean = s / (float)M;
    float var = q / (float)M - mean * mean;
    if (var < 0.f) var = 0.f;
    stats[c] = mean;
    stats[80 + c] = rsqrtf(var + 1e-3f);
}

__global__ void norm_apply(float* __restrict__ X, int M, const float* __restrict__ stats) {
    int idx = blockIdx.x * 256 + threadIdx.x;
    if (idx >= M * F) return;
    int c = idx % F;
    X[idx] = (X[idx] - stats[c]) * stats[80 + c];
}

// ---------------- final V layer: wave-per-row dot(160) ----------------
__global__ __launch_bounds__(256)
void vscore_kernel(const float* __restrict__ H, const float* __restrict__ w,
                   const float* __restrict__ b, float* __restrict__ out, int M) {
    int wid = (blockIdx.x * 256 + threadIdx.x) / 64;
    int lane = threadIdx.x % 64;
    if (wid >= M) return;
    const float* row = H + (size_t)wid * 160;
    float s = 0.f;
    for (int c = lane; c < 160; c += 64) s += row[c] * w[c];
    for (int off = 32; off; off >>= 1) s += __shfl_down(s, off);
    if (lane == 0) out[wid] = s + b[0];
}

// ---------------- loss: per-clause softplus sum -> term, block partials ----------
__global__ __launch_bounds__(256)
void loss_clause(const int* __restrict__ el, const int* __restrict__ off,
                 const float* __restrict__ scores, float* __restrict__ partial, int nc) {
    __shared__ float sd[256];
    int c = blockIdx.x * 256 + threadIdx.x;
    float term = 0.f;
    if (c < nc) {
        int e0 = off[c], e1 = off[c + 1];
        float cs = 0.f;
        for (int e = e0; e < e1; ++e) {
            int lit = el[e];
            float v = (lit < NV) ? scores[lit] : -scores[lit - NV];
            cs += fmaxf(v, 0.f) + log1pf(expf(-fabsf(v)));
        }
        float cv = expf(-cs);
        term = cv * (-logf(1.0f - cv + 1e-8f));
    }
    sd[threadIdx.x] = term;
    __syncthreads();
    for (int s = 128; s; s >>= 1) {
        if (threadIdx.x < s) sd[threadIdx.x] += sd[threadIdx.x + s];
        __syncthreads();
    }
    if (threadIdx.x == 0) partial[blockIdx.x] = sd[0];
}

__global__ void loss_final(const float* __restrict__ partial, int n, float* __restrict__ out) {
    __shared__ float sd[256];
    float s = 0.f;
    for (int i = threadIdx.x; i < n; i += 256) s += partial[i];
    sd[threadIdx.x] = s;
    __syncthreads();
    for (int k = 128; k; k >>= 1) {
        if (threadIdx.x < k) sd[threadIdx.x] += sd[threadIdx.x + k];
        __syncthreads();
    }
    if (threadIdx.x == 0) out[0] = sd[0];
}

// =======================================================================
static inline size_t alignup(size_t x) { return (x + 255) & ~(size_t)255; }

extern "C" void kernel_launch(void* const* d_in, const int* in_sizes, int n_in,
                              void* d_out, int out_size, void* d_ws, size_t ws_size,
                              hipStream_t stream) {
    const int*   el   = (const int*)d_in[0];
    const int*   ec   = (const int*)d_in[1];
    const float* l_init = (const float*)d_in[4];
    const float* c_init = (const float*)d_in[5];
    const float* lc_s = (const float*)d_in[6];
    const float* cl_s = (const float*)d_in[7];
    const float* Cw1 = (const float*)d_in[8],  *Cb1 = (const float*)d_in[9];
    const float* Cw2 = (const float*)d_in[10], *Cb2 = (const float*)d_in[11];
    const float* Lw1 = (const float*)d_in[12], *Lb1 = (const float*)d_in[13];
    const float* Lw2 = (const float*)d_in[14], *Lb2 = (const float*)d_in[15];
    const float* Vw1 = (const float*)d_in[16], *Vb1 = (const float*)d_in[17];
    const float* Vw2 = (const float*)d_in[18], *Vb2 = (const float*)d_in[19];
    const float* Vw3 = (const float*)d_in[20], *Vb3 = (const float*)d_in[21];
    const float* Vw4 = (const float*)d_in[22], *Vb4 = (const float*)d_in[23];
    float* out = (float*)d_out;

    // ---- workspace carve-up (slim: ~249 MB total) ----
    char* p = (char*)d_ws;
    size_t o = 0;
    int*   off = (int*)(p + o);   o += alignup((size_t)(NC + 1) * 4);
    float* L0  = (float*)(p + o); o += alignup((size_t)NL * F * 4);        // 32 MB
    float* L1  = (float*)(p + o); o += alignup((size_t)NL * F * 4);        // 32 MB
    float* Cb  = (float*)(p + o); o += alignup((size_t)NC * F * 4);        // 67.2 MB (single, in-place via chunks)
    float* MSG = (float*)(p + o); o += alignup((size_t)NC * F * 4);        // 67.2 MB (LC / CL / H2, disjoint lifetimes)
    float* H   = (float*)(p + o); o += alignup((size_t)12000000 * 4);      // 48 MB (per-chunk activations)
    float* Psum = (float*)(p + o); o += alignup((size_t)2200 * 80 * 4);
    float* Psq  = (float*)(p + o); o += alignup((size_t)2200 * 80 * 4);
    float* stats = (float*)(p + o); o += alignup(160 * 4);
    float* lossP = (float*)(p + o); o += alignup(1024 * 4);
    (void)ws_size; (void)n_in; (void)in_sizes; (void)out_size;

    // ---- CSR offsets (edge_clause sorted) ----
    build_off<<<(NNZE + 255) / 256, 256, 0, stream>>>(ec, off, NNZE, NC);

    // ---- init L, C ----
    fill_val<<<(NL * F + 255) / 256, 256, 0, stream>>>(L0, NL * F, l_init);
    fill_val<<<(NC * F + 255) / 256, 256, 0, stream>>>(Cb, NC * F, c_init);

    float* Lc = L0, *Ln = L1;
    const int nblkC = (NC + 95) / 96;
    const int nblkL = (NL + 95) / 96;
    const int CCH[4] = {0, 75000, 150000, 210000};   // C-MLP row chunks

    for (int round = 0; round < 4; ++round) {
        // LC_msgs = segsum(L[el], ec) * lc_s   (MSG = LC)
        float* LC = MSG;
        lc_gather<<<(NC * F + 255) / 256, 256, 0, stream>>>(Lc, el, off, lc_s, LC);

        // C MLP, chunked over M, in-place on Cb
        for (int ci = 0; ci < 3; ++ci) {
            int r0 = CCH[ci], mloc = CCH[ci + 1] - r0;
            dim3 g1((mloc + BM - 1) / BM, (160 + BN - 1) / BN);
            gemm_fused<<<g1, 256, 0, stream>>>(Cb + (size_t)r0 * F, LC + (size_t)r0 * F, nullptr,
                                               80, 0, 0, mloc, 160, 160, Cw1, Cb1, H, 1);
            dim3 g2((mloc + BM - 1) / BM, (80 + BN - 1) / BN);
            gemm_fused<<<g2, 256, 0, stream>>>(H, nullptr, nullptr,
                                               160, 0, 0, mloc, 160, 80, Cw2, Cb2, Cb + (size_t)r0 * F, 0);
        }
        // normalize C
        colstats_partial<<<nblkC, 256, 0, stream>>>(Cb, NC, Psum, Psq);
        colstats_final<<<1, 128, 0, stream>>>(Psum, Psq, nblkC, NC, stats);
        norm_apply<<<(NC * F + 255) / 256, 256, 0, stream>>>(Cb, NC, stats);

        // CL_msgs = segsum(C[ec], el) * cl_s   (MSG = CL, atomic scatter)
        float* CL = MSG;
        zero_fill<<<(NL * F + 255) / 256, 256, 0, stream>>>(CL, NL * F);
        cl_scatter<<<(NNZE * F + 255) / 256, 256, 0, stream>>>(Cb, el, ec, cl_s, CL);

        // L MLP, chunked over M (flip reads global rows from Lc; output to Ln)
        for (int ci = 0; ci < 2; ++ci) {
            int r0 = ci * 50000, mloc = 50000;
            dim3 g1((mloc + BM - 1) / BM, (240 + BN - 1) / BN);
            gemm_fused<<<g1, 256, 0, stream>>>(Lc + (size_t)r0 * F, CL + (size_t)r0 * F, Lc,
                                               80, 1, r0, mloc, 240, 240, Lw1, Lb1, H, 1);
            dim3 g2((mloc + BM - 1) / BM, (80 + BN - 1) / BN);
            gemm_fused<<<g2, 256, 0, stream>>>(H, nullptr, nullptr,
                                               240, 0, 0, mloc, 240, 80, Lw2, Lb2, Ln + (size_t)r0 * F, 0);
        }
        // normalize L
        colstats_partial<<<nblkL, 256, 0, stream>>>(Ln, NL, Psum, Psq);
        colstats_final<<<1, 128, 0, stream>>>(Psum, Psq, nblkL, NL, stats);
        norm_apply<<<(NL * F + 255) / 256, 256, 0, stream>>>(Ln, NL, stats);

        // swap L buffers
        float* t = Lc; Lc = Ln; Ln = t;
    }

    // ---- V MLP on [L[:NV] | L[NV:]] ----
    {
        float* H2 = MSG;   // LC/CL dead now
        dim3 g((NV + BM - 1) / BM, (160 + BN - 1) / BN);
        gemm_fused<<<g, 256, 0, stream>>>(Lc, Lc + (size_t)NV * F, nullptr,
                                          80, 0, 0, NV, 160, 160, Vw1, Vb1, H, 1);
        gemm_fused<<<g, 256, 0, stream>>>(H, nullptr, nullptr,
                                          160, 0, 0, NV, 160, 160, Vw2, Vb2, H2, 1);
        gemm_fused<<<g, 256, 0, stream>>>(H2, nullptr, nullptr,
                                          160, 0, 0, NV, 160, 160, Vw3, Vb3, H, 1);
        vscore_kernel<<<(NV * 64 + 255) / 256, 256, 0, stream>>>(H, Vw4, Vb4, out, NV);
    }

    // ---- loss over clauses ----
    {
        int nblk = (NC + 255) / 256;
        loss_clause<<<nblk, 256, 0, stream>>>(el, off, out, lossP, NC);
        loss_final<<<1, 256, 0, stream>>>(lossP, nblk, out + NV);
    }
}

// Round 3
// 6126.327 us; speedup vs baseline: 1.4663x; 1.4663x over previous
//
#include <hip/hip_runtime.h>
#include <hip/hip_bf16.h>

#define NV 50000
#define NL 100000
#define NC 210000
#define NNZE 630000
#define F 80

#define BM 64
#define BN 64
#define BKK 16

// rows per colstats_partial block
#define CS_ROWS 768

// ---------------- offsets from sorted edge_clause ----------------
__global__ void build_off(const int* __restrict__ ec, int* __restrict__ off,
                          int nnz, int nc) {
    int e = blockIdx.x * 256 + threadIdx.x;
    if (e >= nnz) return;
    int c = ec[e];
    if (e == 0) {
        for (int cc = 0; cc <= c; ++cc) off[cc] = 0;
    } else {
        int cp = ec[e - 1];
        for (int cc = cp + 1; cc <= c; ++cc) off[cc] = e;
    }
    if (e == nnz - 1) {
        for (int cc = c + 1; cc <= nc; ++cc) off[cc] = nnz;
    }
}

// ---------------- fills ----------------
__global__ void fill_val(float* __restrict__ p, int n, const float* __restrict__ v) {
    int i = blockIdx.x * 256 + threadIdx.x;
    if (i < n) p[i] = v[0];
}

__global__ void zero_fill(float* __restrict__ p, int n) {
    int i = blockIdx.x * 256 + threadIdx.x;
    if (i < n) p[i] = 0.f;
}

// ---------------- LC gather: per (clause, feature) ----------------
__global__ void lc_gather(const float* __restrict__ L, const int* __restrict__ el,
                          const int* __restrict__ off, const float* __restrict__ scale,
                          float* __restrict__ LC) {
    int idx = blockIdx.x * 256 + threadIdx.x;
    if (idx >= NC * F) return;
    int c = idx / F, f = idx % F;
    int e0 = off[c], e1 = off[c + 1];
    float s = 0.f;
    for (int e = e0; e < e1; ++e)
        s += L[(size_t)el[e] * F + f];
    LC[idx] = s * scale[0];
}

// ---------------- CL scatter: per (edge, feature), atomics ----------------
__global__ void cl_scatter(const float* __restrict__ C, const int* __restrict__ el,
                           const int* __restrict__ ec, const float* __restrict__ scale,
                           float* __restrict__ CL) {
    int idx = blockIdx.x * 256 + threadIdx.x;
    if (idx >= NNZE * F) return;
    int e = idx / F, f = idx % F;
    float v = C[(size_t)ec[e] * F + f] * scale[0];
    atomicAdd(&CL[(size_t)el[e] * F + f], v);
}

// ---------------- fused piecewise GEMM: Out = act(A @ W + b) ----------------
__global__ __launch_bounds__(256)
void gemm_fused(const float* __restrict__ A0, const float* __restrict__ A1,
                const float* __restrict__ A2, int pw, int flip2, int rbase,
                int M, int K, int N,
                const float* __restrict__ W, const float* __restrict__ bias,
                float* __restrict__ Out, int act) {
    __shared__ float As[BKK][BM + 4];
    __shared__ float Bs[BKK][BN + 4];
    int m0 = blockIdx.x * BM, n0 = blockIdx.y * BN;
    int tid = threadIdx.x;
    int tx = tid % 16, ty = tid / 16;
    float acc[4][4] = {};

    for (int k0 = 0; k0 < K; k0 += BKK) {
        {   // A tile: 64 rows x 16 k
            int lk = tid % 16, lm = tid / 16;
            int kg = k0 + lk;
            int piece = kg / pw, kk = kg - piece * pw;
#pragma unroll
            for (int i = 0; i < 4; ++i) {
                int m = lm + i * 16;
                int row = m0 + m;
                float v = 0.f;
                if (row < M) {
                    const float* P;
                    int re = row;
                    if (piece == 0) P = A0;
                    else if (piece == 1) P = A1;
                    else {
                        P = A2;
                        if (flip2) {
                            int g = rbase + row;
                            re = (g < NV) ? g + NV : g - NV;
                        }
                    }
                    v = P[(size_t)re * pw + kk];
                }
                As[lk][m] = v;
            }
        }
        {   // W tile: 16 k x 64 n
            int ln = tid % 64, lk = tid / 64;
#pragma unroll
            for (int i = 0; i < 4; ++i) {
                int k = lk + i * 4;
                int n = n0 + ln;
                Bs[k][ln] = (n < N) ? W[(size_t)(k0 + k) * N + n] : 0.f;
            }
        }
        __syncthreads();
#pragma unroll
        for (int kk = 0; kk < BKK; ++kk) {
            float a[4], b[4];
#pragma unroll
            for (int i = 0; i < 4; ++i) a[i] = As[kk][ty * 4 + i];
#pragma unroll
            for (int j = 0; j < 4; ++j) b[j] = Bs[kk][tx * 4 + j];
#pragma unroll
            for (int i = 0; i < 4; ++i)
#pragma unroll
                for (int j = 0; j < 4; ++j) acc[i][j] += a[i] * b[j];
        }
        __syncthreads();
    }
#pragma unroll
    for (int i = 0; i < 4; ++i) {
        int row = m0 + ty * 4 + i;
        if (row >= M) continue;
#pragma unroll
        for (int j = 0; j < 4; ++j) {
            int col = n0 + tx * 4 + j;
            if (col >= N) continue;
            float v = acc[i][j] + bias[col];
            if (act) v = fminf(fmaxf(v, 0.f), 6.f);
            Out[(size_t)row * N + col] = v;
        }
    }
}

// ---------------- column stats (mean/var over axis 0), 2-stage deterministic ----
// Each block: 768 rows. tid -> col = tid%80, slot = tid/80 (0..2; 16 threads idle).
__global__ __launch_bounds__(256)
void colstats_partial(const float* __restrict__ X, int M,
                      float* __restrict__ Psum, float* __restrict__ Psq) {
    __shared__ float sd[256], qd[256];
    int tid = threadIdx.x;
    int col = tid % 80;
    int slot = tid / 80;     // 0..3 (slot 3 inactive)
    int base = blockIdx.x * CS_ROWS;
    float s = 0.f, q = 0.f;
    if (slot < 3) {
        for (int i = 0; i < CS_ROWS / 3; ++i) {
            int r = base + slot + i * 3;
            if (r < M) {
                float v = X[(size_t)r * F + col];
                s += v; q += v * v;
            }
        }
    }
    sd[tid] = s; qd[tid] = q;
    __syncthreads();
    if (tid < 80) {
        float ts = sd[tid] + sd[tid + 80] + sd[tid + 160];
        float tq = qd[tid] + qd[tid + 80] + qd[tid + 160];
        Psum[(size_t)blockIdx.x * 80 + tid] = ts;
        Psq [(size_t)blockIdx.x * 80 + tid] = tq;
    }
}

// One block per column (80 blocks), 256 threads grid-stride over partial blocks.
__global__ __launch_bounds__(256)
void colstats_final(const float* __restrict__ Psum, const float* __restrict__ Psq,
                    int nblk, int M, float* __restrict__ stats) {
    __shared__ float sd[256], qd[256];
    int c = blockIdx.x;
    int tid = threadIdx.x;
    float s = 0.f, q = 0.f;
    for (int b = tid; b < nblk; b += 256) {
        s += Psum[(size_t)b * 80 + c];
        q += Psq [(size_t)b * 80 + c];
    }
    sd[tid] = s; qd[tid] = q;
    __syncthreads();
    for (int k = 128; k; k >>= 1) {
        if (tid < k) { sd[tid] += sd[tid + k]; qd[tid] += qd[tid + k]; }
        __syncthreads();
    }
    if (tid == 0) {
        float mean = sd[0] / (float)M;
        float var = qd[0] / (float)M - mean * mean;
        if (var < 0.f) var = 0.f;
        stats[c] = mean;
        stats[80 + c] = rsqrtf(var + 1e-3f);
    }
}

__global__ void norm_apply(float* __restrict__ X, int M, const float* __restrict__ stats) {
    int idx = blockIdx.x * 256 + threadIdx.x;
    if (idx >= M * F) return;
    int c = idx % F;
    X[idx] = (X[idx] - stats[c]) * stats[80 + c];
}

// ---------------- final V layer: wave-per-row dot(160) ----------------
__global__ __launch_bounds__(256)
void vscore_kernel(const float* __restrict__ H, const float* __restrict__ w,
                   const float* __restrict__ b, float* __restrict__ out, int M) {
    int wid = (blockIdx.x * 256 + threadIdx.x) / 64;
    int lane = threadIdx.x % 64;
    if (wid >= M) return;
    const float* row = H + (size_t)wid * 160;
    float s = 0.f;
    for (int c = lane; c < 160; c += 64) s += row[c] * w[c];
    for (int off = 32; off; off >>= 1) s += __shfl_down(s, off);
    if (lane == 0) out[wid] = s + b[0];
}

// ---------------- loss: per-clause softplus sum -> term, block partials ----------
__global__ __launch_bounds__(256)
void loss_clause(const int* __restrict__ el, const int* __restrict__ off,
                 const float* __restrict__ scores, float* __restrict__ partial, int nc) {
    __shared__ float sd[256];
    int c = blockIdx.x * 256 + threadIdx.x;
    float term = 0.f;
    if (c < nc) {
        int e0 = off[c], e1 = off[c + 1];
        float cs = 0.f;
        for (int e = e0; e < e1; ++e) {
            int lit = el[e];
            float v = (lit < NV) ? scores[lit] : -scores[lit - NV];
            cs += fmaxf(v, 0.f) + log1pf(expf(-fabsf(v)));
        }
        float cv = expf(-cs);
        term = cv * (-logf(1.0f - cv + 1e-8f));
    }
    sd[threadIdx.x] = term;
    __syncthreads();
    for (int s = 128; s; s >>= 1) {
        if (threadIdx.x < s) sd[threadIdx.x] += sd[threadIdx.x + s];
        __syncthreads();
    }
    if (threadIdx.x == 0) partial[blockIdx.x] = sd[0];
}

__global__ void loss_final(const float* __restrict__ partial, int n, float* __restrict__ out) {
    __shared__ float sd[256];
    float s = 0.f;
    for (int i = threadIdx.x; i < n; i += 256) s += partial[i];
    sd[threadIdx.x] = s;
    __syncthreads();
    for (int k = 128; k; k >>= 1) {
        if (threadIdx.x < k) sd[threadIdx.x] += sd[threadIdx.x + k];
        __syncthreads();
    }
    if (threadIdx.x == 0) out[0] = sd[0];
}

// =======================================================================
static inline size_t alignup(size_t x) { return (x + 255) & ~(size_t)255; }

extern "C" void kernel_launch(void* const* d_in, const int* in_sizes, int n_in,
                              void* d_out, int out_size, void* d_ws, size_t ws_size,
                              hipStream_t stream) {
    const int*   el   = (const int*)d_in[0];
    const int*   ec   = (const int*)d_in[1];
    const float* l_init = (const float*)d_in[4];
    const float* c_init = (const float*)d_in[5];
    const float* lc_s = (const float*)d_in[6];
    const float* cl_s = (const float*)d_in[7];
    const float* Cw1 = (const float*)d_in[8],  *Cb1 = (const float*)d_in[9];
    const float* Cw2 = (const float*)d_in[10], *Cb2 = (const float*)d_in[11];
    const float* Lw1 = (const float*)d_in[12], *Lb1 = (const float*)d_in[13];
    const float* Lw2 = (const float*)d_in[14], *Lb2 = (const float*)d_in[15];
    const float* Vw1 = (const float*)d_in[16], *Vb1 = (const float*)d_in[17];
    const float* Vw2 = (const float*)d_in[18], *Vb2 = (const float*)d_in[19];
    const float* Vw3 = (const float*)d_in[20], *Vb3 = (const float*)d_in[21];
    const float* Vw4 = (const float*)d_in[22], *Vb4 = (const float*)d_in[23];
    float* out = (float*)d_out;

    // ---- workspace carve-up (slim: ~249 MB total) ----
    char* p = (char*)d_ws;
    size_t o = 0;
    int*   off = (int*)(p + o);   o += alignup((size_t)(NC + 1) * 4);
    float* L0  = (float*)(p + o); o += alignup((size_t)NL * F * 4);        // 32 MB
    float* L1  = (float*)(p + o); o += alignup((size_t)NL * F * 4);        // 32 MB
    float* Cb  = (float*)(p + o); o += alignup((size_t)NC * F * 4);        // 67.2 MB
    float* MSG = (float*)(p + o); o += alignup((size_t)NC * F * 4);        // 67.2 MB (LC/CL/H2)
    float* H   = (float*)(p + o); o += alignup((size_t)12000000 * 4);      // 48 MB
    float* Psum = (float*)(p + o); o += alignup((size_t)300 * 80 * 4);
    float* Psq  = (float*)(p + o); o += alignup((size_t)300 * 80 * 4);
    float* stats = (float*)(p + o); o += alignup(160 * 4);
    float* lossP = (float*)(p + o); o += alignup(1024 * 4);
    (void)ws_size; (void)n_in; (void)in_sizes; (void)out_size;

    // ---- CSR offsets (edge_clause sorted) ----
    build_off<<<(NNZE + 255) / 256, 256, 0, stream>>>(ec, off, NNZE, NC);

    // ---- init L, C ----
    fill_val<<<(NL * F + 255) / 256, 256, 0, stream>>>(L0, NL * F, l_init);
    fill_val<<<(NC * F + 255) / 256, 256, 0, stream>>>(Cb, NC * F, c_init);

    float* Lc = L0, *Ln = L1;
    const int nblkC = (NC + CS_ROWS - 1) / CS_ROWS;   // 274
    const int nblkL = (NL + CS_ROWS - 1) / CS_ROWS;   // 131
    const int CCH[4] = {0, 75000, 150000, 210000};

    for (int round = 0; round < 4; ++round) {
        // LC_msgs = segsum(L[el], ec) * lc_s   (MSG = LC)
        float* LC = MSG;
        lc_gather<<<(NC * F + 255) / 256, 256, 0, stream>>>(Lc, el, off, lc_s, LC);

        // C MLP, chunked over M, in-place on Cb
        for (int ci = 0; ci < 3; ++ci) {
            int r0 = CCH[ci], mloc = CCH[ci + 1] - r0;
            dim3 g1((mloc + BM - 1) / BM, (160 + BN - 1) / BN);
            gemm_fused<<<g1, 256, 0, stream>>>(Cb + (size_t)r0 * F, LC + (size_t)r0 * F, nullptr,
                                               80, 0, 0, mloc, 160, 160, Cw1, Cb1, H, 1);
            dim3 g2((mloc + BM - 1) / BM, (80 + BN - 1) / BN);
            gemm_fused<<<g2, 256, 0, stream>>>(H, nullptr, nullptr,
                                               160, 0, 0, mloc, 160, 80, Cw2, Cb2, Cb + (size_t)r0 * F, 0);
        }
        // normalize C
        colstats_partial<<<nblkC, 256, 0, stream>>>(Cb, NC, Psum, Psq);
        colstats_final<<<80, 256, 0, stream>>>(Psum, Psq, nblkC, NC, stats);
        norm_apply<<<(NC * F + 255) / 256, 256, 0, stream>>>(Cb, NC, stats);

        // CL_msgs = segsum(C[ec], el) * cl_s   (MSG = CL, atomic scatter)
        float* CL = MSG;
        zero_fill<<<(NL * F + 255) / 256, 256, 0, stream>>>(CL, NL * F);
        cl_scatter<<<(NNZE * F + 255) / 256, 256, 0, stream>>>(Cb, el, ec, cl_s, CL);

        // L MLP, chunked over M (flip reads global rows from Lc; output to Ln)
        for (int ci = 0; ci < 2; ++ci) {
            int r0 = ci * 50000, mloc = 50000;
            dim3 g1((mloc + BM - 1) / BM, (240 + BN - 1) / BN);
            gemm_fused<<<g1, 256, 0, stream>>>(Lc + (size_t)r0 * F, CL + (size_t)r0 * F, Lc,
                                               80, 1, r0, mloc, 240, 240, Lw1, Lb1, H, 1);
            dim3 g2((mloc + BM - 1) / BM, (80 + BN - 1) / BN);
            gemm_fused<<<g2, 256, 0, stream>>>(H, nullptr, nullptr,
                                               240, 0, 0, mloc, 240, 80, Lw2, Lb2, Ln + (size_t)r0 * F, 0);
        }
        // normalize L
        colstats_partial<<<nblkL, 256, 0, stream>>>(Ln, NL, Psum, Psq);
        colstats_final<<<80, 256, 0, stream>>>(Psum, Psq, nblkL, NL, stats);
        norm_apply<<<(NL * F + 255) / 256, 256, 0, stream>>>(Ln, NL, stats);

        // swap L buffers
        float* t = Lc; Lc = Ln; Ln = t;
    }

    // ---- V MLP on [L[:NV] | L[NV:]] ----
    {
        float* H2 = MSG;   // LC/CL dead now
        dim3 g((NV + BM - 1) / BM, (160 + BN - 1) / BN);
        gemm_fused<<<g, 256, 0, stream>>>(Lc, Lc + (size_t)NV * F, nullptr,
                                          80, 0, 0, NV, 160, 160, Vw1, Vb1, H, 1);
        gemm_fused<<<g, 256, 0, stream>>>(H, nullptr, nullptr,
                                          160, 0, 0, NV, 160, 160, Vw2, Vb2, H2, 1);
        gemm_fused<<<g, 256, 0, stream>>>(H2, nullptr, nullptr,
                                          160, 0, 0, NV, 160, 160, Vw3, Vb3, H, 1);
        vscore_kernel<<<(NV * 64 + 255) / 256, 256, 0, stream>>>(H, Vw4, Vb4, out, NV);
    }

    // ---- loss over clauses ----
    {
        int nblk = (NC + 255) / 256;
        loss_clause<<<nblk, 256, 0, stream>>>(el, off, out, lossP, NC);
        loss_final<<<1, 256, 0, stream>>>(lossP, nblk, out + NV);
    }
}

// Round 4
// 4414.977 us; speedup vs baseline: 2.0346x; 1.3876x over previous
//
#include <hip/hip_runtime.h>
#include <hip/hip_bf16.h>

#define NV 50000
#define NL 100000
#define NC 210000
#define NNZE 630000
#define F 80

// rows per colstats_partial block
#define CS_ROWS 768

// MFMA GEMM tile
#define TBM 256
#define TBN 80
#define TBK 32

typedef __attribute__((ext_vector_type(8))) short s8v;
typedef __attribute__((ext_vector_type(4))) float f4v;
typedef __attribute__((ext_vector_type(4))) unsigned short us4;

__device__ inline unsigned short bf16_hi(float x) {
    return (unsigned short)(__builtin_bit_cast(unsigned int, x) >> 16);
}
__device__ inline float bf16_to_f(unsigned short h) {
    return __builtin_bit_cast(float, (unsigned int)h << 16);
}

// ---------------- offsets from sorted edge_clause ----------------
__global__ void build_off(const int* __restrict__ ec, int* __restrict__ off,
                          int nnz, int nc) {
    int e = blockIdx.x * 256 + threadIdx.x;
    if (e >= nnz) return;
    int c = ec[e];
    if (e == 0) {
        for (int cc = 0; cc <= c; ++cc) off[cc] = 0;
    } else {
        int cp = ec[e - 1];
        for (int cc = cp + 1; cc <= c; ++cc) off[cc] = e;
    }
    if (e == nnz - 1) {
        for (int cc = c + 1; cc <= nc; ++cc) off[cc] = nnz;
    }
}

// ---------------- fills ----------------
__global__ void fill_val(float* __restrict__ p, int n, const float* __restrict__ v) {
    int i = blockIdx.x * 256 + threadIdx.x;
    if (i < n) p[i] = v[0];
}

__global__ void zero_fill(float* __restrict__ p, int n) {
    int i = blockIdx.x * 256 + threadIdx.x;
    if (i < n) p[i] = 0.f;
}

// ---------------- LC gather: per (clause, feature) ----------------
__global__ void lc_gather(const float* __restrict__ L, const int* __restrict__ el,
                          const int* __restrict__ off, const float* __restrict__ scale,
                          float* __restrict__ LC) {
    int idx = blockIdx.x * 256 + threadIdx.x;
    if (idx >= NC * F) return;
    int c = idx / F, f = idx % F;
    int e0 = off[c], e1 = off[c + 1];
    float s = 0.f;
    for (int e = e0; e < e1; ++e)
        s += L[(size_t)el[e] * F + f];
    LC[idx] = s * scale[0];
}

// ---------------- CL scatter: per (edge, feature), atomics ----------------
__global__ void cl_scatter(const float* __restrict__ C, const int* __restrict__ el,
                           const int* __restrict__ ec, const float* __restrict__ scale,
                           float* __restrict__ CL) {
    int idx = blockIdx.x * 256 + threadIdx.x;
    if (idx >= NNZE * F) return;
    int e = idx / F, f = idx % F;
    float v = C[(size_t)ec[e] * F + f] * scale[0];
    atomicAdd(&CL[(size_t)el[e] * F + f], v);
}

// ---------------- MFMA split-bf16 piecewise GEMM ----------------
// Out[M][N] = act(A @ W + bias), A = concat of pieces (width pw) along K.
// Pieces 0/1 indexed by local row; piece 2 with flip2 uses global row rbase+row,
// flipped (L_flip). W is [K][N] row-major fp32. N must be a multiple of 80.
// Each fp32 input is split a = hi + lo (bf16 each); product uses 3 MFMAs:
// hi*hi + lo*hi + hi*lo  (error ~2^-16 relative, fp32-equivalent).
__global__ __launch_bounds__(256, 2)
void gemm_mfma(const float* __restrict__ A0, const float* __restrict__ A1,
               const float* __restrict__ A2, int pw, int flip2, int rbase,
               int M, int K, int N,
               const float* __restrict__ W, const float* __restrict__ bias,
               float* __restrict__ Out, int act) {
    __shared__ __align__(16) unsigned short AsH[TBM * TBK];
    __shared__ __align__(16) unsigned short AsL[TBM * TBK];
    __shared__ __align__(16) unsigned short BsH[TBN * TBK];
    __shared__ __align__(16) unsigned short BsL[TBN * TBK];

    const int t = threadIdx.x;
    const int m0 = blockIdx.x * TBM;
    const int n0 = blockIdx.y * TBN;
    const int w = t >> 6;          // wave 0..3 -> rows [w*64, w*64+64)
    const int l = t & 63;
    const int lr = l & 15;         // fragment row/col within 16
    const int lk = (l >> 4) * 8;   // k offset within 32

    f4v acc[4][5];
#pragma unroll
    for (int i = 0; i < 4; ++i)
#pragma unroll
        for (int j = 0; j < 5; ++j) acc[i][j] = (f4v)0.f;

    for (int k0 = 0; k0 < K; k0 += TBK) {
        // ---- stage A tile: 256 rows x 32 k (hi/lo bf16) ----
#pragma unroll
        for (int i = 0; i < 8; ++i) {
            int tau = i * 256 + t;
            int r = tau >> 3, q = tau & 7;
            int row = m0 + r;
            int kg = k0 + q * 4;
            float4 v = make_float4(0.f, 0.f, 0.f, 0.f);
            if (row < M && kg < K) {
                int piece = (kg >= pw) + (kg >= 2 * pw);
                int kk = kg - piece * pw;
                const float* P;
                int re = row;
                if (piece == 0) P = A0;
                else if (piece == 1) P = A1;
                else {
                    P = A2;
                    if (flip2) {
                        int g = rbase + row;
                        re = (g < NV) ? g + NV : g - NV;
                    }
                }
                v = *(const float4*)&P[(size_t)re * pw + kk];
            }
            us4 hv, lv;
            float f0[4] = {v.x, v.y, v.z, v.w};
#pragma unroll
            for (int j = 0; j < 4; ++j) {
                unsigned short h = bf16_hi(f0[j]);
                hv[j] = (short)h;
                lv[j] = (short)bf16_hi(f0[j] - bf16_to_f(h));
            }
            *(us4*)&AsH[r * TBK + q * 4] = hv;
            *(us4*)&AsL[r * TBK + q * 4] = lv;
        }
        // ---- stage B tile: 80 n x 32 k, transposed from W[K][N] ----
#pragma unroll
        for (int i = 0; i < 3; ++i) {
            int tau = i * 256 + t;
            if (tau < 640) {
                int n = tau % 80, kq = tau / 80;
                us4 hv, lv;
#pragma unroll
                for (int j = 0; j < 4; ++j) {
                    int k = k0 + kq * 4 + j;
                    float x = (k < K) ? W[(size_t)k * N + n0 + n] : 0.f;
                    unsigned short h = bf16_hi(x);
                    hv[j] = (short)h;
                    lv[j] = (short)bf16_hi(x - bf16_to_f(h));
                }
                *(us4*)&BsH[n * TBK + kq * 4] = hv;
                *(us4*)&BsL[n * TBK + kq * 4] = lv;
            }
        }
        __syncthreads();

        // ---- fragments + MFMA ----
        s8v aH[4], aL[4], bH[5], bL[5];
#pragma unroll
        for (int mf = 0; mf < 4; ++mf) {
            int ar = w * 64 + mf * 16 + lr;
            aH[mf] = *(const s8v*)&AsH[ar * TBK + lk];
            aL[mf] = *(const s8v*)&AsL[ar * TBK + lk];
        }
#pragma unroll
        for (int nf = 0; nf < 5; ++nf) {
            int br = nf * 16 + lr;
            bH[nf] = *(const s8v*)&BsH[br * TBK + lk];
            bL[nf] = *(const s8v*)&BsL[br * TBK + lk];
        }
#pragma unroll
        for (int mf = 0; mf < 4; ++mf)
#pragma unroll
            for (int nf = 0; nf < 5; ++nf) {
                acc[mf][nf] = __builtin_amdgcn_mfma_f32_16x16x32_bf16(aH[mf], bH[nf], acc[mf][nf], 0, 0, 0);
                acc[mf][nf] = __builtin_amdgcn_mfma_f32_16x16x32_bf16(aL[mf], bH[nf], acc[mf][nf], 0, 0, 0);
                acc[mf][nf] = __builtin_amdgcn_mfma_f32_16x16x32_bf16(aH[mf], bL[nf], acc[mf][nf], 0, 0, 0);
            }
        __syncthreads();
    }

    // ---- epilogue: D row=(l>>4)*4+reg, col=l&15 (m89-verified) ----
#pragma unroll
    for (int mf = 0; mf < 4; ++mf) {
        int rowb = m0 + w * 64 + mf * 16 + (l >> 4) * 4;
#pragma unroll
        for (int nf = 0; nf < 5; ++nf) {
            int col = n0 + nf * 16 + lr;
            float bv = bias[col];
#pragma unroll
            for (int r = 0; r < 4; ++r) {
                int row = rowb + r;
                if (row < M) {
                    float v = acc[mf][nf][r] + bv;
                    if (act) v = fminf(fmaxf(v, 0.f), 6.f);
                    Out[(size_t)row * N + col] = v;
                }
            }
        }
    }
}

// ---------------- column stats (mean/var over axis 0), 2-stage deterministic ----
__global__ __launch_bounds__(256)
void colstats_partial(const float* __restrict__ X, int M,
                      float* __restrict__ Psum, float* __restrict__ Psq) {
    __shared__ float sd[256], qd[256];
    int tid = threadIdx.x;
    int col = tid % 80;
    int slot = tid / 80;
    int base = blockIdx.x * CS_ROWS;
    float s = 0.f, q = 0.f;
    if (slot < 3) {
        for (int i = 0; i < CS_ROWS / 3; ++i) {
            int r = base + slot + i * 3;
            if (r < M) {
                float v = X[(size_t)r * F + col];
                s += v; q += v * v;
            }
        }
    }
    sd[tid] = s; qd[tid] = q;
    __syncthreads();
    if (tid < 80) {
        float ts = sd[tid] + sd[tid + 80] + sd[tid + 160];
        float tq = qd[tid] + qd[tid + 80] + qd[tid + 160];
        Psum[(size_t)blockIdx.x * 80 + tid] = ts;
        Psq [(size_t)blockIdx.x * 80 + tid] = tq;
    }
}

__global__ __launch_bounds__(256)
void colstats_final(const float* __restrict__ Psum, const float* __restrict__ Psq,
                    int nblk, int M, float* __restrict__ stats) {
    __shared__ float sd[256], qd[256];
    int c = blockIdx.x;
    int tid = threadIdx.x;
    float s = 0.f, q = 0.f;
    for (int b = tid; b < nblk; b += 256) {
        s += Psum[(size_t)b * 80 + c];
        q += Psq [(size_t)b * 80 + c];
    }
    sd[tid] = s; qd[tid] = q;
    __syncthreads();
    for (int k = 128; k; k >>= 1) {
        if (tid < k) { sd[tid] += sd[tid + k]; qd[tid] += qd[tid + k]; }
        __syncthreads();
    }
    if (tid == 0) {
        float mean = sd[0] / (float)M;
        float var = qd[0] / (float)M - mean * mean;
        if (var < 0.f) var = 0.f;
        stats[c] = mean;
        stats[80 + c] = rsqrtf(var + 1e-3f);
    }
}

__global__ void norm_apply(float* __restrict__ X, int M, const float* __restrict__ stats) {
    int idx = blockIdx.x * 256 + threadIdx.x;
    if (idx >= M * F) return;
    int c = idx % F;
    X[idx] = (X[idx] - stats[c]) * stats[80 + c];
}

// ---------------- final V layer: wave-per-row dot(160) ----------------
__global__ __launch_bounds__(256)
void vscore_kernel(const float* __restrict__ H, const float* __restrict__ w,
                   const float* __restrict__ b, float* __restrict__ out, int M) {
    int wid = (blockIdx.x * 256 + threadIdx.x) / 64;
    int lane = threadIdx.x % 64;
    if (wid >= M) return;
    const float* row = H + (size_t)wid * 160;
    float s = 0.f;
    for (int c = lane; c < 160; c += 64) s += row[c] * w[c];
    for (int off = 32; off; off >>= 1) s += __shfl_down(s, off);
    if (lane == 0) out[wid] = s + b[0];
}

// ---------------- loss ----------------
__global__ __launch_bounds__(256)
void loss_clause(const int* __restrict__ el, const int* __restrict__ off,
                 const float* __restrict__ scores, float* __restrict__ partial, int nc) {
    __shared__ float sd[256];
    int c = blockIdx.x * 256 + threadIdx.x;
    float term = 0.f;
    if (c < nc) {
        int e0 = off[c], e1 = off[c + 1];
        float cs = 0.f;
        for (int e = e0; e < e1; ++e) {
            int lit = el[e];
            float v = (lit < NV) ? scores[lit] : -scores[lit - NV];
            cs += fmaxf(v, 0.f) + log1pf(expf(-fabsf(v)));
        }
        float cv = expf(-cs);
        term = cv * (-logf(1.0f - cv + 1e-8f));
    }
    sd[threadIdx.x] = term;
    __syncthreads();
    for (int s = 128; s; s >>= 1) {
        if (threadIdx.x < s) sd[threadIdx.x] += sd[threadIdx.x + s];
        __syncthreads();
    }
    if (threadIdx.x == 0) partial[blockIdx.x] = sd[0];
}

__global__ void loss_final(const float* __restrict__ partial, int n, float* __restrict__ out) {
    __shared__ float sd[256];
    float s = 0.f;
    for (int i = threadIdx.x; i < n; i += 256) s += partial[i];
    sd[threadIdx.x] = s;
    __syncthreads();
    for (int k = 128; k; k >>= 1) {
        if (threadIdx.x < k) sd[threadIdx.x] += sd[threadIdx.x + k];
        __syncthreads();
    }
    if (threadIdx.x == 0) out[0] = sd[0];
}

// =======================================================================
static inline size_t alignup(size_t x) { return (x + 255) & ~(size_t)255; }

extern "C" void kernel_launch(void* const* d_in, const int* in_sizes, int n_in,
                              void* d_out, int out_size, void* d_ws, size_t ws_size,
                              hipStream_t stream) {
    const int*   el   = (const int*)d_in[0];
    const int*   ec   = (const int*)d_in[1];
    const float* l_init = (const float*)d_in[4];
    const float* c_init = (const float*)d_in[5];
    const float* lc_s = (const float*)d_in[6];
    const float* cl_s = (const float*)d_in[7];
    const float* Cw1 = (const float*)d_in[8],  *Cb1 = (const float*)d_in[9];
    const float* Cw2 = (const float*)d_in[10], *Cb2 = (const float*)d_in[11];
    const float* Lw1 = (const float*)d_in[12], *Lb1 = (const float*)d_in[13];
    const float* Lw2 = (const float*)d_in[14], *Lb2 = (const float*)d_in[15];
    const float* Vw1 = (const float*)d_in[16], *Vb1 = (const float*)d_in[17];
    const float* Vw2 = (const float*)d_in[18], *Vb2 = (const float*)d_in[19];
    const float* Vw3 = (const float*)d_in[20], *Vb3 = (const float*)d_in[21];
    const float* Vw4 = (const float*)d_in[22], *Vb4 = (const float*)d_in[23];
    float* out = (float*)d_out;

    // ---- workspace carve-up (~249 MB) ----
    char* p = (char*)d_ws;
    size_t o = 0;
    int*   off = (int*)(p + o);   o += alignup((size_t)(NC + 1) * 4);
    float* L0  = (float*)(p + o); o += alignup((size_t)NL * F * 4);
    float* L1  = (float*)(p + o); o += alignup((size_t)NL * F * 4);
    float* Cb  = (float*)(p + o); o += alignup((size_t)NC * F * 4);
    float* MSG = (float*)(p + o); o += alignup((size_t)NC * F * 4);
    float* H   = (float*)(p + o); o += alignup((size_t)12000000 * 4);
    float* Psum = (float*)(p + o); o += alignup((size_t)300 * 80 * 4);
    float* Psq  = (float*)(p + o); o += alignup((size_t)300 * 80 * 4);
    float* stats = (float*)(p + o); o += alignup(160 * 4);
    float* lossP = (float*)(p + o); o += alignup(1024 * 4);
    (void)ws_size; (void)n_in; (void)in_sizes; (void)out_size;

    build_off<<<(NNZE + 255) / 256, 256, 0, stream>>>(ec, off, NNZE, NC);
    fill_val<<<(NL * F + 255) / 256, 256, 0, stream>>>(L0, NL * F, l_init);
    fill_val<<<(NC * F + 255) / 256, 256, 0, stream>>>(Cb, NC * F, c_init);

    float* Lc = L0, *Ln = L1;
    const int nblkC = (NC + CS_ROWS - 1) / CS_ROWS;
    const int nblkL = (NL + CS_ROWS - 1) / CS_ROWS;
    const int CCH[4] = {0, 70000, 140000, 210000};

    for (int round = 0; round < 4; ++round) {
        // LC_msgs
        float* LC = MSG;
        lc_gather<<<(NC * F + 255) / 256, 256, 0, stream>>>(Lc, el, off, lc_s, LC);

        // C MLP, chunked, in-place on Cb
        for (int ci = 0; ci < 3; ++ci) {
            int r0 = CCH[ci], mloc = CCH[ci + 1] - r0;
            dim3 g1((mloc + TBM - 1) / TBM, 160 / TBN);
            gemm_mfma<<<g1, 256, 0, stream>>>(Cb + (size_t)r0 * F, LC + (size_t)r0 * F, nullptr,
                                              80, 0, 0, mloc, 160, 160, Cw1, Cb1, H, 1);
            dim3 g2((mloc + TBM - 1) / TBM, 80 / TBN);
            gemm_mfma<<<g2, 256, 0, stream>>>(H, nullptr, nullptr,
                                              160, 0, 0, mloc, 160, 80, Cw2, Cb2, Cb + (size_t)r0 * F, 0);
        }
        colstats_partial<<<nblkC, 256, 0, stream>>>(Cb, NC, Psum, Psq);
        colstats_final<<<80, 256, 0, stream>>>(Psum, Psq, nblkC, NC, stats);
        norm_apply<<<(NC * F + 255) / 256, 256, 0, stream>>>(Cb, NC, stats);

        // CL_msgs
        float* CL = MSG;
        zero_fill<<<(NL * F + 255) / 256, 256, 0, stream>>>(CL, NL * F);
        cl_scatter<<<(NNZE * F + 255) / 256, 256, 0, stream>>>(Cb, el, ec, cl_s, CL);

        // L MLP, chunked
        for (int ci = 0; ci < 2; ++ci) {
            int r0 = ci * 50000, mloc = 50000;
            dim3 g1((mloc + TBM - 1) / TBM, 240 / TBN);
            gemm_mfma<<<g1, 256, 0, stream>>>(Lc + (size_t)r0 * F, CL + (size_t)r0 * F, Lc,
                                              80, 1, r0, mloc, 240, 240, Lw1, Lb1, H, 1);
            dim3 g2((mloc + TBM - 1) / TBM, 80 / TBN);
            gemm_mfma<<<g2, 256, 0, stream>>>(H, nullptr, nullptr,
                                              240, 0, 0, mloc, 240, 80, Lw2, Lb2, Ln + (size_t)r0 * F, 0);
        }
        colstats_partial<<<nblkL, 256, 0, stream>>>(Ln, NL, Psum, Psq);
        colstats_final<<<80, 256, 0, stream>>>(Psum, Psq, nblkL, NL, stats);
        norm_apply<<<(NL * F + 255) / 256, 256, 0, stream>>>(Ln, NL, stats);

        float* t = Lc; Lc = Ln; Ln = t;
    }

    // ---- V MLP ----
    {
        float* H2 = MSG;
        dim3 g((NV + TBM - 1) / TBM, 160 / TBN);
        gemm_mfma<<<g, 256, 0, stream>>>(Lc, Lc + (size_t)NV * F, nullptr,
                                         80, 0, 0, NV, 160, 160, Vw1, Vb1, H, 1);
        gemm_mfma<<<g, 256, 0, stream>>>(H, nullptr, nullptr,
                                         160, 0, 0, NV, 160, 160, Vw2, Vb2, H2, 1);
        gemm_mfma<<<g, 256, 0, stream>>>(H2, nullptr, nullptr,
                                         160, 0, 0, NV, 160, 160, Vw3, Vb3, H, 1);
        vscore_kernel<<<(NV * 64 + 255) / 256, 256, 0, stream>>>(H, Vw4, Vb4, out, NV);
    }

    // ---- loss ----
    {
        int nblk = (NC + 255) / 256;
        loss_clause<<<nblk, 256, 0, stream>>>(el, off, out, lossP, NC);
        loss_final<<<1, 256, 0, stream>>>(lossP, nblk, out + NV);
    }
}

// Round 5
// 4088.812 us; speedup vs baseline: 2.1969x; 1.0798x over previous
//
#include <hip/hip_runtime.h>
#include <hip/hip_bf16.h>

#define NV 50000
#define NL 100000
#define NC 210000
#define NNZE 630000
#define F 80

// rows per colstats_partial block
#define CS_ROWS 768

// MFMA GEMM tile
#define TBM 256
#define TBN 80
#define TBK 32
#define LDA 40   // padded LDS row stride in shorts (80B = 20 dwords, gcd(20,32)=4 -> 2-way = free)

typedef __attribute__((ext_vector_type(8))) short s8v;
typedef __attribute__((ext_vector_type(4))) float f4v;
typedef __attribute__((ext_vector_type(8))) unsigned short us8;

__device__ inline unsigned short bf16_hi(float x) {
    return (unsigned short)(__builtin_bit_cast(unsigned int, x) >> 16);
}
__device__ inline float bf16_to_f(unsigned short h) {
    return __builtin_bit_cast(float, (unsigned int)h << 16);
}

// ---------------- offsets from sorted edge_clause ----------------
__global__ void build_off(const int* __restrict__ ec, int* __restrict__ off,
                          int nnz, int nc) {
    int e = blockIdx.x * 256 + threadIdx.x;
    if (e >= nnz) return;
    int c = ec[e];
    if (e == 0) {
        for (int cc = 0; cc <= c; ++cc) off[cc] = 0;
    } else {
        int cp = ec[e - 1];
        for (int cc = cp + 1; cc <= c; ++cc) off[cc] = e;
    }
    if (e == nnz - 1) {
        for (int cc = c + 1; cc <= nc; ++cc) off[cc] = nnz;
    }
}

// ---------------- fills ----------------
__global__ void fill_val(float* __restrict__ p, int n, const float* __restrict__ v) {
    int i = blockIdx.x * 256 + threadIdx.x;
    if (i < n) p[i] = v[0];
}

__global__ void zero_fill(float* __restrict__ p, int n) {
    int i = blockIdx.x * 256 + threadIdx.x;
    if (i < n) p[i] = 0.f;
}

// ---------------- LC gather: per (clause, feature) ----------------
__global__ void lc_gather(const float* __restrict__ L, const int* __restrict__ el,
                          const int* __restrict__ off, const float* __restrict__ scale,
                          float* __restrict__ LC) {
    int idx = blockIdx.x * 256 + threadIdx.x;
    if (idx >= NC * F) return;
    int c = idx / F, f = idx % F;
    int e0 = off[c], e1 = off[c + 1];
    float s = 0.f;
    for (int e = e0; e < e1; ++e)
        s += L[(size_t)el[e] * F + f];
    LC[idx] = s * scale[0];
}

// ---------------- CL scatter: per (edge, feature), atomics ----------------
__global__ void cl_scatter(const float* __restrict__ C, const int* __restrict__ el,
                           const int* __restrict__ ec, const float* __restrict__ scale,
                           float* __restrict__ CL) {
    int idx = blockIdx.x * 256 + threadIdx.x;
    if (idx >= NNZE * F) return;
    int e = idx / F, f = idx % F;
    float v = C[(size_t)ec[e] * F + f] * scale[0];
    atomicAdd(&CL[(size_t)el[e] * F + f], v);
}

// ---------------- MFMA split-bf16 piecewise GEMM ----------------
// Out[M][N] = act(A @ W + bias), A = concat of pieces (width pw) along K.
// Pieces 0/1 indexed by local row; piece 2 with flip2 uses global row rbase+row,
// flipped (L_flip). W is [K][N] row-major fp32. N must be a multiple of 80.
// a = hi + lo (bf16 each); product = hi*hi + lo*hi + hi*lo  (~2^-16 rel err).
// LDS rows padded to LDA=40 shorts: ds_read_b128 lands 2 lanes/bank = conflict-free.
__global__ __launch_bounds__(256, 2)
void gemm_mfma(const float* __restrict__ A0, const float* __restrict__ A1,
               const float* __restrict__ A2, int pw, int flip2, int rbase,
               int M, int K, int N,
               const float* __restrict__ W, const float* __restrict__ bias,
               float* __restrict__ Out, int act) {
    __shared__ __align__(16) unsigned short AsH[TBM * LDA];
    __shared__ __align__(16) unsigned short AsL[TBM * LDA];
    __shared__ __align__(16) unsigned short BsH[TBN * LDA];
    __shared__ __align__(16) unsigned short BsL[TBN * LDA];

    const int t = threadIdx.x;
    const int m0 = blockIdx.x * TBM;
    const int n0 = blockIdx.y * TBN;
    const int w = t >> 6;          // wave 0..3 -> rows [w*64, w*64+64)
    const int l = t & 63;
    const int lr = l & 15;         // fragment row/col within 16
    const int lk = (l >> 4) * 8;   // k offset within 32

    f4v acc[4][5];
#pragma unroll
    for (int i = 0; i < 4; ++i)
#pragma unroll
        for (int j = 0; j < 5; ++j) acc[i][j] = (f4v)0.f;

    for (int k0 = 0; k0 < K; k0 += TBK) {
        // ---- stage A tile: 256 rows x 32 k; unit = 8 consecutive k (16B LDS write)
        // 8-k chunks never straddle piece boundaries (pw multiples of 8).
#pragma unroll
        for (int i = 0; i < 4; ++i) {
            int u = i * 256 + t;           // 0..1023
            int r = u >> 2, q = u & 3;
            int row = m0 + r;
            int kg = k0 + q * 8;
            float f0[8] = {0.f, 0.f, 0.f, 0.f, 0.f, 0.f, 0.f, 0.f};
            if (row < M && kg < K) {
                int piece = (kg >= pw) + (kg >= 2 * pw);
                int kk = kg - piece * pw;
                const float* P;
                int re = row;
                if (piece == 0) P = A0;
                else if (piece == 1) P = A1;
                else {
                    P = A2;
                    if (flip2) {
                        int g = rbase + row;
                        re = (g < NV) ? g + NV : g - NV;
                    }
                }
                const float* src = &P[(size_t)re * pw + kk];
                float4 v0 = *(const float4*)src;
                float4 v1 = *(const float4*)(src + 4);
                f0[0] = v0.x; f0[1] = v0.y; f0[2] = v0.z; f0[3] = v0.w;
                f0[4] = v1.x; f0[5] = v1.y; f0[6] = v1.z; f0[7] = v1.w;
            }
            us8 hv, lv;
#pragma unroll
            for (int j = 0; j < 8; ++j) {
                unsigned short h = bf16_hi(f0[j]);
                hv[j] = h;
                lv[j] = bf16_hi(f0[j] - bf16_to_f(h));
            }
            *(us8*)&AsH[r * LDA + q * 8] = hv;
            *(us8*)&AsL[r * LDA + q * 8] = lv;
        }
        // ---- stage B tile: 80 n x 32 k, transposed from W[K][N] ----
#pragma unroll
        for (int i = 0; i < 2; ++i) {
            int u = i * 256 + t;
            if (u < 320) {                 // 80 n * 4 chunks
                int n = u >> 2, q = u & 3;
                us8 hv, lv;
#pragma unroll
                for (int j = 0; j < 8; ++j) {
                    int k = k0 + q * 8 + j;
                    float x = (k < K) ? W[(size_t)k * N + n0 + n] : 0.f;
                    unsigned short h = bf16_hi(x);
                    hv[j] = h;
                    lv[j] = bf16_hi(x - bf16_to_f(h));
                }
                *(us8*)&BsH[n * LDA + q * 8] = hv;
                *(us8*)&BsL[n * LDA + q * 8] = lv;
            }
        }
        __syncthreads();

        // ---- fragments + MFMA ----
        s8v aH[4], aL[4], bH[5], bL[5];
#pragma unroll
        for (int mf = 0; mf < 4; ++mf) {
            int ar = w * 64 + mf * 16 + lr;
            aH[mf] = *(const s8v*)&AsH[ar * LDA + lk];
            aL[mf] = *(const s8v*)&AsL[ar * LDA + lk];
        }
#pragma unroll
        for (int nf = 0; nf < 5; ++nf) {
            int br = nf * 16 + lr;
            bH[nf] = *(const s8v*)&BsH[br * LDA + lk];
            bL[nf] = *(const s8v*)&BsL[br * LDA + lk];
        }
#pragma unroll
        for (int mf = 0; mf < 4; ++mf)
#pragma unroll
            for (int nf = 0; nf < 5; ++nf) {
                acc[mf][nf] = __builtin_amdgcn_mfma_f32_16x16x32_bf16(aH[mf], bH[nf], acc[mf][nf], 0, 0, 0);
                acc[mf][nf] = __builtin_amdgcn_mfma_f32_16x16x32_bf16(aL[mf], bH[nf], acc[mf][nf], 0, 0, 0);
                acc[mf][nf] = __builtin_amdgcn_mfma_f32_16x16x32_bf16(aH[mf], bL[nf], acc[mf][nf], 0, 0, 0);
            }
        __syncthreads();
    }

    // ---- epilogue: D row=(l>>4)*4+reg, col=l&15 (m89-verified) ----
#pragma unroll
    for (int mf = 0; mf < 4; ++mf) {
        int rowb = m0 + w * 64 + mf * 16 + (l >> 4) * 4;
#pragma unroll
        for (int nf = 0; nf < 5; ++nf) {
            int col = n0 + nf * 16 + lr;
            float bv = bias[col];
#pragma unroll
            for (int r = 0; r < 4; ++r) {
                int row = rowb + r;
                if (row < M) {
                    float v = acc[mf][nf][r] + bv;
                    if (act) v = fminf(fmaxf(v, 0.f), 6.f);
                    Out[(size_t)row * N + col] = v;
                }
            }
        }
    }
}

// ---------------- column stats (mean/var over axis 0), 2-stage deterministic ----
__global__ __launch_bounds__(256)
void colstats_partial(const float* __restrict__ X, int M,
                      float* __restrict__ Psum, float* __restrict__ Psq) {
    __shared__ float sd[256], qd[256];
    int tid = threadIdx.x;
    int col = tid % 80;
    int slot = tid / 80;
    int base = blockIdx.x * CS_ROWS;
    float s = 0.f, q = 0.f;
    if (slot < 3) {
        for (int i = 0; i < CS_ROWS / 3; ++i) {
            int r = base + slot + i * 3;
            if (r < M) {
                float v = X[(size_t)r * F + col];
                s += v; q += v * v;
            }
        }
    }
    sd[tid] = s; qd[tid] = q;
    __syncthreads();
    if (tid < 80) {
        float ts = sd[tid] + sd[tid + 80] + sd[tid + 160];
        float tq = qd[tid] + qd[tid + 80] + qd[tid + 160];
        Psum[(size_t)blockIdx.x * 80 + tid] = ts;
        Psq [(size_t)blockIdx.x * 80 + tid] = tq;
    }
}

__global__ __launch_bounds__(256)
void colstats_final(const float* __restrict__ Psum, const float* __restrict__ Psq,
                    int nblk, int M, float* __restrict__ stats) {
    __shared__ float sd[256], qd[256];
    int c = blockIdx.x;
    int tid = threadIdx.x;
    float s = 0.f, q = 0.f;
    for (int b = tid; b < nblk; b += 256) {
        s += Psum[(size_t)b * 80 + c];
        q += Psq [(size_t)b * 80 + c];
    }
    sd[tid] = s; qd[tid] = q;
    __syncthreads();
    for (int k = 128; k; k >>= 1) {
        if (tid < k) { sd[tid] += sd[tid + k]; qd[tid] += qd[tid + k]; }
        __syncthreads();
    }
    if (tid == 0) {
        float mean = sd[0] / (float)M;
        float var = qd[0] / (float)M - mean * mean;
        if (var < 0.f) var = 0.f;
        stats[c] = mean;
        stats[80 + c] = rsqrtf(var + 1e-3f);
    }
}

__global__ void norm_apply(float* __restrict__ X, int M, const float* __restrict__ stats) {
    int idx = blockIdx.x * 256 + threadIdx.x;
    if (idx >= M * F) return;
    int c = idx % F;
    X[idx] = (X[idx] - stats[c]) * stats[80 + c];
}

// ---------------- final V layer: wave-per-row dot(160) ----------------
__global__ __launch_bounds__(256)
void vscore_kernel(const float* __restrict__ H, const float* __restrict__ w,
                   const float* __restrict__ b, float* __restrict__ out, int M) {
    int wid = (blockIdx.x * 256 + threadIdx.x) / 64;
    int lane = threadIdx.x % 64;
    if (wid >= M) return;
    const float* row = H + (size_t)wid * 160;
    float s = 0.f;
    for (int c = lane; c < 160; c += 64) s += row[c] * w[c];
    for (int off = 32; off; off >>= 1) s += __shfl_down(s, off);
    if (lane == 0) out[wid] = s + b[0];
}

// ---------------- loss ----------------
__global__ __launch_bounds__(256)
void loss_clause(const int* __restrict__ el, const int* __restrict__ off,
                 const float* __restrict__ scores, float* __restrict__ partial, int nc) {
    __shared__ float sd[256];
    int c = blockIdx.x * 256 + threadIdx.x;
    float term = 0.f;
    if (c < nc) {
        int e0 = off[c], e1 = off[c + 1];
        float cs = 0.f;
        for (int e = e0; e < e1; ++e) {
            int lit = el[e];
            float v = (lit < NV) ? scores[lit] : -scores[lit - NV];
            cs += fmaxf(v, 0.f) + log1pf(expf(-fabsf(v)));
        }
        float cv = expf(-cs);
        term = cv * (-logf(1.0f - cv + 1e-8f));
    }
    sd[threadIdx.x] = term;
    __syncthreads();
    for (int s = 128; s; s >>= 1) {
        if (threadIdx.x < s) sd[threadIdx.x] += sd[threadIdx.x + s];
        __syncthreads();
    }
    if (threadIdx.x == 0) partial[blockIdx.x] = sd[0];
}

__global__ void loss_final(const float* __restrict__ partial, int n, float* __restrict__ out) {
    __shared__ float sd[256];
    float s = 0.f;
    for (int i = threadIdx.x; i < n; i += 256) s += partial[i];
    sd[threadIdx.x] = s;
    __syncthreads();
    for (int k = 128; k; k >>= 1) {
        if (threadIdx.x < k) sd[threadIdx.x] += sd[threadIdx.x + k];
        __syncthreads();
    }
    if (threadIdx.x == 0) out[0] = sd[0];
}

// =======================================================================
static inline size_t alignup(size_t x) { return (x + 255) & ~(size_t)255; }

extern "C" void kernel_launch(void* const* d_in, const int* in_sizes, int n_in,
                              void* d_out, int out_size, void* d_ws, size_t ws_size,
                              hipStream_t stream) {
    const int*   el   = (const int*)d_in[0];
    const int*   ec   = (const int*)d_in[1];
    const float* l_init = (const float*)d_in[4];
    const float* c_init = (const float*)d_in[5];
    const float* lc_s = (const float*)d_in[6];
    const float* cl_s = (const float*)d_in[7];
    const float* Cw1 = (const float*)d_in[8],  *Cb1 = (const float*)d_in[9];
    const float* Cw2 = (const float*)d_in[10], *Cb2 = (const float*)d_in[11];
    const float* Lw1 = (const float*)d_in[12], *Lb1 = (const float*)d_in[13];
    const float* Lw2 = (const float*)d_in[14], *Lb2 = (const float*)d_in[15];
    const float* Vw1 = (const float*)d_in[16], *Vb1 = (const float*)d_in[17];
    const float* Vw2 = (const float*)d_in[18], *Vb2 = (const float*)d_in[19];
    const float* Vw3 = (const float*)d_in[20], *Vb3 = (const float*)d_in[21];
    const float* Vw4 = (const float*)d_in[22], *Vb4 = (const float*)d_in[23];
    float* out = (float*)d_out;

    // ---- workspace carve-up (~249 MB) ----
    char* p = (char*)d_ws;
    size_t o = 0;
    int*   off = (int*)(p + o);   o += alignup((size_t)(NC + 1) * 4);
    float* L0  = (float*)(p + o); o += alignup((size_t)NL * F * 4);
    float* L1  = (float*)(p + o); o += alignup((size_t)NL * F * 4);
    float* Cb  = (float*)(p + o); o += alignup((size_t)NC * F * 4);
    float* MSG = (float*)(p + o); o += alignup((size_t)NC * F * 4);
    float* H   = (float*)(p + o); o += alignup((size_t)12000000 * 4);
    float* Psum = (float*)(p + o); o += alignup((size_t)300 * 80 * 4);
    float* Psq  = (float*)(p + o); o += alignup((size_t)300 * 80 * 4);
    float* stats = (float*)(p + o); o += alignup(160 * 4);
    float* lossP = (float*)(p + o); o += alignup(1024 * 4);
    (void)ws_size; (void)n_in; (void)in_sizes; (void)out_size;

    build_off<<<(NNZE + 255) / 256, 256, 0, stream>>>(ec, off, NNZE, NC);
    fill_val<<<(NL * F + 255) / 256, 256, 0, stream>>>(L0, NL * F, l_init);
    fill_val<<<(NC * F + 255) / 256, 256, 0, stream>>>(Cb, NC * F, c_init);

    float* Lc = L0, *Ln = L1;
    const int nblkC = (NC + CS_ROWS - 1) / CS_ROWS;
    const int nblkL = (NL + CS_ROWS - 1) / CS_ROWS;
    const int CCH[4] = {0, 70000, 140000, 210000};

    for (int round = 0; round < 4; ++round) {
        // LC_msgs
        float* LC = MSG;
        lc_gather<<<(NC * F + 255) / 256, 256, 0, stream>>>(Lc, el, off, lc_s, LC);

        // C MLP, chunked, in-place on Cb
        for (int ci = 0; ci < 3; ++ci) {
            int r0 = CCH[ci], mloc = CCH[ci + 1] - r0;
            dim3 g1((mloc + TBM - 1) / TBM, 160 / TBN);
            gemm_mfma<<<g1, 256, 0, stream>>>(Cb + (size_t)r0 * F, LC + (size_t)r0 * F, nullptr,
                                              80, 0, 0, mloc, 160, 160, Cw1, Cb1, H, 1);
            dim3 g2((mloc + TBM - 1) / TBM, 80 / TBN);
            gemm_mfma<<<g2, 256, 0, stream>>>(H, nullptr, nullptr,
                                              160, 0, 0, mloc, 160, 80, Cw2, Cb2, Cb + (size_t)r0 * F, 0);
        }
        colstats_partial<<<nblkC, 256, 0, stream>>>(Cb, NC, Psum, Psq);
        colstats_final<<<80, 256, 0, stream>>>(Psum, Psq, nblkC, NC, stats);
        norm_apply<<<(NC * F + 255) / 256, 256, 0, stream>>>(Cb, NC, stats);

        // CL_msgs
        float* CL = MSG;
        zero_fill<<<(NL * F + 255) / 256, 256, 0, stream>>>(CL, NL * F);
        cl_scatter<<<(NNZE * F + 255) / 256, 256, 0, stream>>>(Cb, el, ec, cl_s, CL);

        // L MLP, chunked
        for (int ci = 0; ci < 2; ++ci) {
            int r0 = ci * 50000, mloc = 50000;
            dim3 g1((mloc + TBM - 1) / TBM, 240 / TBN);
            gemm_mfma<<<g1, 256, 0, stream>>>(Lc + (size_t)r0 * F, CL + (size_t)r0 * F, Lc,
                                              80, 1, r0, mloc, 240, 240, Lw1, Lb1, H, 1);
            dim3 g2((mloc + TBM - 1) / TBM, 80 / TBN);
            gemm_mfma<<<g2, 256, 0, stream>>>(H, nullptr, nullptr,
                                              240, 0, 0, mloc, 240, 80, Lw2, Lb2, Ln + (size_t)r0 * F, 0);
        }
        colstats_partial<<<nblkL, 256, 0, stream>>>(Ln, NL, Psum, Psq);
        colstats_final<<<80, 256, 0, stream>>>(Psum, Psq, nblkL, NL, stats);
        norm_apply<<<(NL * F + 255) / 256, 256, 0, stream>>>(Ln, NL, stats);

        float* t = Lc; Lc = Ln; Ln = t;
    }

    // ---- V MLP ----
    {
        float* H2 = MSG;
        dim3 g((NV + TBM - 1) / TBM, 160 / TBN);
        gemm_mfma<<<g, 256, 0, stream>>>(Lc, Lc + (size_t)NV * F, nullptr,
                                         80, 0, 0, NV, 160, 160, Vw1, Vb1, H, 1);
        gemm_mfma<<<g, 256, 0, stream>>>(H, nullptr, nullptr,
                                         160, 0, 0, NV, 160, 160, Vw2, Vb2, H2, 1);
        gemm_mfma<<<g, 256, 0, stream>>>(H2, nullptr, nullptr,
                                         160, 0, 0, NV, 160, 160, Vw3, Vb3, H, 1);
        vscore_kernel<<<(NV * 64 + 255) / 256, 256, 0, stream>>>(H, Vw4, Vb4, out, NV);
    }

    // ---- loss ----
    {
        int nblk = (NC + 255) / 256;
        loss_clause<<<nblk, 256, 0, stream>>>(el, off, out, lossP, NC);
        loss_final<<<1, 256, 0, stream>>>(lossP, nblk, out + NV);
    }
}

// Round 7
// 3505.449 us; speedup vs baseline: 2.5625x; 1.1664x over previous
//
#include <hip/hip_runtime.h>
#include <hip/hip_bf16.h>

#define NV 50000
#define NL 100000
#define NC 210000
#define NNZE 630000
#define F 80

#define CS_ROWS 768

// MFMA GEMM tile
#define TBM 192
#define TBN 80
#define TBK 32
#define LDA 40   // padded LDS row stride in shorts

typedef __attribute__((ext_vector_type(8))) short s8v;
typedef __attribute__((ext_vector_type(4))) float f4v;
typedef __attribute__((ext_vector_type(8))) unsigned short us8;

__device__ inline unsigned short bf16_hi(float x) {
    return (unsigned short)(__builtin_bit_cast(unsigned int, x) >> 16);
}
__device__ inline float bf16_to_f(unsigned short h) {
    return __builtin_bit_cast(float, (unsigned int)h << 16);
}

// ---------------- offsets from sorted edge_clause ----------------
__global__ void build_off(const int* __restrict__ ec, int* __restrict__ off,
                          int nnz, int nc) {
    int e = blockIdx.x * 256 + threadIdx.x;
    if (e >= nnz) return;
    int c = ec[e];
    if (e == 0) {
        for (int cc = 0; cc <= c; ++cc) off[cc] = 0;
    } else {
        int cp = ec[e - 1];
        for (int cc = cp + 1; cc <= c; ++cc) off[cc] = e;
    }
    if (e == nnz - 1) {
        for (int cc = c + 1; cc <= nc; ++cc) off[cc] = nnz;
    }
}

// ---------------- fills ----------------
__global__ void fill_val(float* __restrict__ p, int n, const float* __restrict__ v) {
    int i = blockIdx.x * 256 + threadIdx.x;
    if (i < n) p[i] = v[0];
}
__global__ void zero_int(int* __restrict__ p, int n) {
    int i = blockIdx.x * 256 + threadIdx.x;
    if (i < n) p[i] = 0;
}

// ---------------- lit-CSR build (hist -> scan -> scatter -> sort) ----------------
__global__ void hist_lit(const int* __restrict__ el, int* __restrict__ cnt) {
    int e = blockIdx.x * 256 + threadIdx.x;
    if (e < NNZE) atomicAdd(&cnt[el[e]], 1);
}

__global__ __launch_bounds__(256)
void scan_lit(const int* __restrict__ cnt, int* __restrict__ loff) {
    __shared__ int ps[256];
    int t = threadIdx.x;
    const int CH = (NL + 255) / 256;   // 391
    int a = t * CH, b = a + CH; if (b > NL) b = NL;
    int s = 0;
    for (int i = a; i < b; ++i) s += cnt[i];
    ps[t] = s;
    __syncthreads();
    for (int off = 1; off < 256; off <<= 1) {
        int v = (t >= off) ? ps[t - off] : 0;
        __syncthreads();
        ps[t] += v;
        __syncthreads();
    }
    int run = t ? ps[t - 1] : 0;
    for (int i = a; i < b; ++i) { loff[i] = run; run += cnt[i]; }
    if (t == 255) loff[NL] = run;
}

__global__ void scatter_lit(const int* __restrict__ el, const int* __restrict__ ec,
                            const int* __restrict__ loff, int* __restrict__ cur,
                            int* __restrict__ litc) {
    int e = blockIdx.x * 256 + threadIdx.x;
    if (e >= NNZE) return;
    int l = el[e];
    int pos = loff[l] + atomicAdd(&cur[l], 1);
    litc[pos] = ec[e];
}

// Insertion-sort each literal's clause segment -> deterministic content
// (atomicAdd ordering becomes irrelevant; duplicate keys are interchangeable).
__global__ void seg_sort(const int* __restrict__ loff, int* __restrict__ litc) {
    int l = blockIdx.x * 256 + threadIdx.x;
    if (l >= NL) return;
    int a = loff[l], b = loff[l + 1];
    for (int i = a + 1; i < b; ++i) {
        int key = litc[i];
        int j = i - 1;
        while (j >= a && litc[j] > key) { litc[j + 1] = litc[j]; --j; }
        litc[j + 1] = key;
    }
}

// ---------------- weight pre-split: W[K][N] fp32 -> Wh/Wl[N][K] bf16 ----------------
__global__ void split_w(const float* __restrict__ W, int K, int N,
                        unsigned short* __restrict__ Wh, unsigned short* __restrict__ Wl) {
    int idx = blockIdx.x * 256 + threadIdx.x;
    if (idx >= K * N) return;
    int k = idx / N, n = idx % N;
    float x = W[idx];
    unsigned short h = bf16_hi(x);
    Wh[(size_t)n * K + k] = h;
    Wl[(size_t)n * K + k] = bf16_hi(x - bf16_to_f(h));
}

// ---------------- LC gather: per (clause, 4-feature) ----------------
__global__ void lc_gather(const float* __restrict__ L, const int* __restrict__ el,
                          const int* __restrict__ off, const float* __restrict__ scale,
                          float* __restrict__ LC) {
    int idx = blockIdx.x * 256 + threadIdx.x;
    if (idx >= NC * 20) return;
    int c = idx / 20, f4 = idx % 20;
    int e0 = off[c], e1 = off[c + 1];
    float4 s = make_float4(0.f, 0.f, 0.f, 0.f);
    for (int e = e0; e < e1; ++e) {
        const float4 v = *(const float4*)&L[(size_t)el[e] * F + f4 * 4];
        s.x += v.x; s.y += v.y; s.z += v.z; s.w += v.w;
    }
    float sc = scale[0];
    s.x *= sc; s.y *= sc; s.z *= sc; s.w *= sc;
    *(float4*)&LC[(size_t)c * F + f4 * 4] = s;
}

// ---------------- CL gather: per (lit, 4-feature), via lit-CSR ----------------
__global__ void cl_gather(const float* __restrict__ C, const int* __restrict__ loff,
                          const int* __restrict__ litc, const float* __restrict__ scale,
                          float* __restrict__ CL) {
    int idx = blockIdx.x * 256 + threadIdx.x;
    if (idx >= NL * 20) return;
    int lit = idx / 20, f4 = idx % 20;
    int e0 = loff[lit], e1 = loff[lit + 1];
    float4 s = make_float4(0.f, 0.f, 0.f, 0.f);
    for (int e = e0; e < e1; ++e) {
        const float4 v = *(const float4*)&C[(size_t)litc[e] * F + f4 * 4];
        s.x += v.x; s.y += v.y; s.z += v.z; s.w += v.w;
    }
    float sc = scale[0];
    s.x *= sc; s.y *= sc; s.z *= sc; s.w *= sc;
    *(float4*)&CL[(size_t)lit * F + f4 * 4] = s;
}

// ---------------- MFMA split-bf16 piecewise GEMM ----------------
// Out = act(A @ W + bias); A = concat pieces (width pw); W pre-split to
// Wh/Wl [N][K] bf16. a=hi+lo; product = aH*bH + aL*bH + aH*bL.
// TBM=192, 4 waves x 48 rows; 3 blocks/CU; A-tile register prefetch.
__global__ __launch_bounds__(256, 3)
void gemm_mfma(const float* __restrict__ A0, const float* __restrict__ A1,
               const float* __restrict__ A2, int pw, int flip2, int rbase,
               int M, int K, int N,
               const unsigned short* __restrict__ Wh, const unsigned short* __restrict__ Wl,
               const float* __restrict__ bias, float* __restrict__ Out, int act) {
    __shared__ __align__(16) unsigned short AsH[TBM * LDA];
    __shared__ __align__(16) unsigned short AsL[TBM * LDA];
    __shared__ __align__(16) unsigned short BsH[TBN * LDA];
    __shared__ __align__(16) unsigned short BsL[TBN * LDA];

    const int t = threadIdx.x;
    const int m0 = blockIdx.x * TBM;
    const int n0 = blockIdx.y * TBN;
    const int w = t >> 6;          // wave 0..3 -> rows [w*48, w*48+48)
    const int l = t & 63;
    const int lr = l & 15;
    const int lk = (l >> 4) * 8;
    const int q = t & 3;           // A-stage k-chunk (8 k each)
    const int rb = t >> 2;         // A-stage row base

    f4v acc[3][5];
#pragma unroll
    for (int i = 0; i < 3; ++i)
#pragma unroll
        for (int j = 0; j < 5; ++j) acc[i][j] = (f4v)0.f;

    float4 pa[3][2];

#define ALOAD(K0)                                                              \
    {                                                                          \
        _Pragma("unroll")                                                      \
        for (int i = 0; i < 3; ++i) {                                          \
            int row = m0 + i * 64 + rb;                                        \
            int kg = (K0) + q * 8;                                             \
            float4 z = make_float4(0.f, 0.f, 0.f, 0.f);                        \
            pa[i][0] = z; pa[i][1] = z;                                        \
            if (row < M && kg < K) {                                           \
                int piece = (kg >= pw) + (kg >= 2 * pw);                       \
                int kk = kg - piece * pw;                                      \
                const float* P = piece == 0 ? A0 : piece == 1 ? A1 : A2;       \
                int re = row;                                                  \
                if (piece == 2 && flip2) {                                     \
                    int g = rbase + row;                                       \
                    re = (g < NV) ? g + NV : g - NV;                           \
                }                                                              \
                const float* src = P + (size_t)re * pw + kk;                   \
                pa[i][0] = *(const float4*)src;                                \
                pa[i][1] = *(const float4*)(src + 4);                          \
            }                                                                  \
        }                                                                      \
    }

    const int nk = (K + TBK - 1) / TBK;
    ALOAD(0);

    for (int s = 0; s < nk; ++s) {
        const int k0 = s * TBK;
        // ---- commit A (convert prefetched regs -> LDS) ----
#pragma unroll
        for (int i = 0; i < 3; ++i) {
            float f0[8] = {pa[i][0].x, pa[i][0].y, pa[i][0].z, pa[i][0].w,
                           pa[i][1].x, pa[i][1].y, pa[i][1].z, pa[i][1].w};
            us8 hv, lv;
#pragma unroll
            for (int j = 0; j < 8; ++j) {
                unsigned short h = bf16_hi(f0[j]);
                hv[j] = h;
                lv[j] = bf16_hi(f0[j] - bf16_to_f(h));
            }
            int r = i * 64 + rb;
            *(us8*)&AsH[r * LDA + q * 8] = hv;
            *(us8*)&AsL[r * LDA + q * 8] = lv;
        }
        // ---- commit B (pre-split global -> LDS; pure copy) ----
#pragma unroll
        for (int i = 0; i < 3; ++i) {
            int u = i * 256 + t;
            if (u < 640) {
                int hi = (u < 320);
                int c = hi ? u : u - 320;
                int n = c >> 2, cq = c & 3;
                int kg = k0 + cq * 8;
                us8 v = {0, 0, 0, 0, 0, 0, 0, 0};
                if (kg < K)
                    v = *(const us8*)&(hi ? Wh : Wl)[(size_t)(n0 + n) * K + kg];
                *(us8*)&(hi ? BsH : BsL)[n * LDA + cq * 8] = v;
            }
        }
        __syncthreads();

        s8v aH[3], aL[3], bH[5], bL[5];
#pragma unroll
        for (int mf = 0; mf < 3; ++mf) {
            int ar = w * 48 + mf * 16 + lr;
            aH[mf] = *(const s8v*)&AsH[ar * LDA + lk];
            aL[mf] = *(const s8v*)&AsL[ar * LDA + lk];
        }
#pragma unroll
        for (int nf = 0; nf < 5; ++nf) {
            int br = nf * 16 + lr;
            bH[nf] = *(const s8v*)&BsH[br * LDA + lk];
            bL[nf] = *(const s8v*)&BsL[br * LDA + lk];
        }
        if (s + 1 < nk) ALOAD(k0 + TBK);   // prefetch spans MFMA + barrier
#pragma unroll
        for (int mf = 0; mf < 3; ++mf)
#pragma unroll
            for (int nf = 0; nf < 5; ++nf) {
                acc[mf][nf] = __builtin_amdgcn_mfma_f32_16x16x32_bf16(aH[mf], bH[nf], acc[mf][nf], 0, 0, 0);
                acc[mf][nf] = __builtin_amdgcn_mfma_f32_16x16x32_bf16(aL[mf], bH[nf], acc[mf][nf], 0, 0, 0);
                acc[mf][nf] = __builtin_amdgcn_mfma_f32_16x16x32_bf16(aH[mf], bL[nf], acc[mf][nf], 0, 0, 0);
            }
        __syncthreads();
    }
#undef ALOAD

    // ---- epilogue ----
#pragma unroll
    for (int mf = 0; mf < 3; ++mf) {
        int rowb = m0 + w * 48 + mf * 16 + (l >> 4) * 4;
#pragma unroll
        for (int nf = 0; nf < 5; ++nf) {
            int col = n0 + nf * 16 + lr;
            float bv = bias[col];
#pragma unroll
            for (int r = 0; r < 4; ++r) {
                int row = rowb + r;
                if (row < M) {
                    float v = acc[mf][nf][r] + bv;
                    if (act) v = fminf(fmaxf(v, 0.f), 6.f);
                    Out[(size_t)row * N + col] = v;
                }
            }
        }
    }
}

// ---------------- column stats ----------------
__global__ __launch_bounds__(256)
void colstats_partial(const float* __restrict__ X, int M,
                      float* __restrict__ Psum, float* __restrict__ Psq) {
    __shared__ float sd[256], qd[256];
    int tid = threadIdx.x;
    int col = tid % 80;
    int slot = tid / 80;
    int base = blockIdx.x * CS_ROWS;
    float s = 0.f, q = 0.f;
    if (slot < 3) {
        for (int i = 0; i < CS_ROWS / 3; ++i) {
            int r = base + slot + i * 3;
            if (r < M) {
                float v = X[(size_t)r * F + col];
                s += v; q += v * v;
            }
        }
    }
    sd[tid] = s; qd[tid] = q;
    __syncthreads();
    if (tid < 80) {
        Psum[(size_t)blockIdx.x * 80 + tid] = sd[tid] + sd[tid + 80] + sd[tid + 160];
        Psq [(size_t)blockIdx.x * 80 + tid] = qd[tid] + qd[tid + 80] + qd[tid + 160];
    }
}

__global__ __launch_bounds__(256)
void colstats_final(const float* __restrict__ Psum, const float* __restrict__ Psq,
                    int nblk, int M, float* __restrict__ stats) {
    __shared__ float sd[256], qd[256];
    int c = blockIdx.x;
    int tid = threadIdx.x;
    float s = 0.f, q = 0.f;
    for (int b = tid; b < nblk; b += 256) {
        s += Psum[(size_t)b * 80 + c];
        q += Psq [(size_t)b * 80 + c];
    }
    sd[tid] = s; qd[tid] = q;
    __syncthreads();
    for (int k = 128; k; k >>= 1) {
        if (tid < k) { sd[tid] += sd[tid + k]; qd[tid] += qd[tid + k]; }
        __syncthreads();
    }
    if (tid == 0) {
        float mean = sd[0] / (float)M;
        float var = qd[0] / (float)M - mean * mean;
        if (var < 0.f) var = 0.f;
        stats[c] = mean;
        stats[80 + c] = rsqrtf(var + 1e-3f);
    }
}

__global__ void norm_apply(float* __restrict__ X, int M, const float* __restrict__ stats) {
    int idx = blockIdx.x * 256 + threadIdx.x;
    if (idx >= M * F) return;
    int c = idx % F;
    X[idx] = (X[idx] - stats[c]) * stats[80 + c];
}

// ---------------- final V layer ----------------
__global__ __launch_bounds__(256)
void vscore_kernel(const float* __restrict__ H, const float* __restrict__ w,
                   const float* __restrict__ b, float* __restrict__ out, int M) {
    int wid = (blockIdx.x * 256 + threadIdx.x) / 64;
    int lane = threadIdx.x % 64;
    if (wid >= M) return;
    const float* row = H + (size_t)wid * 160;
    float s = 0.f;
    for (int c = lane; c < 160; c += 64) s += row[c] * w[c];
    for (int off = 32; off; off >>= 1) s += __shfl_down(s, off);
    if (lane == 0) out[wid] = s + b[0];
}

// ---------------- loss ----------------
__global__ __launch_bounds__(256)
void loss_clause(const int* __restrict__ el, const int* __restrict__ off,
                 const float* __restrict__ scores, float* __restrict__ partial, int nc) {
    __shared__ float sd[256];
    int c = blockIdx.x * 256 + threadIdx.x;
    float term = 0.f;
    if (c < nc) {
        int e0 = off[c], e1 = off[c + 1];
        float cs = 0.f;
        for (int e = e0; e < e1; ++e) {
            int lit = el[e];
            float v = (lit < NV) ? scores[lit] : -scores[lit - NV];
            cs += fmaxf(v, 0.f) + log1pf(expf(-fabsf(v)));
        }
        float cv = expf(-cs);
        term = cv * (-logf(1.0f - cv + 1e-8f));
    }
    sd[threadIdx.x] = term;
    __syncthreads();
    for (int s = 128; s; s >>= 1) {
        if (threadIdx.x < s) sd[threadIdx.x] += sd[threadIdx.x + s];
        __syncthreads();
    }
    if (threadIdx.x == 0) partial[blockIdx.x] = sd[0];
}

__global__ void loss_final(const float* __restrict__ partial, int n, float* __restrict__ out) {
    __shared__ float sd[256];
    float s = 0.f;
    for (int i = threadIdx.x; i < n; i += 256) s += partial[i];
    sd[threadIdx.x] = s;
    __syncthreads();
    for (int k = 128; k; k >>= 1) {
        if (threadIdx.x < k) sd[threadIdx.x] += sd[threadIdx.x + k];
        __syncthreads();
    }
    if (threadIdx.x == 0) out[0] = sd[0];
}

// =======================================================================
static inline size_t alignup(size_t x) { return (x + 255) & ~(size_t)255; }

extern "C" void kernel_launch(void* const* d_in, const int* in_sizes, int n_in,
                              void* d_out, int out_size, void* d_ws, size_t ws_size,
                              hipStream_t stream) {
    const int*   el   = (const int*)d_in[0];
    const int*   ec   = (const int*)d_in[1];
    const float* l_init = (const float*)d_in[4];
    const float* c_init = (const float*)d_in[5];
    const float* lc_s = (const float*)d_in[6];
    const float* cl_s = (const float*)d_in[7];
    const float* Cw1 = (const float*)d_in[8],  *Cb1 = (const float*)d_in[9];
    const float* Cw2 = (const float*)d_in[10], *Cb2 = (const float*)d_in[11];
    const float* Lw1 = (const float*)d_in[12], *Lb1 = (const float*)d_in[13];
    const float* Lw2 = (const float*)d_in[14], *Lb2 = (const float*)d_in[15];
    const float* Vw1 = (const float*)d_in[16], *Vb1 = (const float*)d_in[17];
    const float* Vw2 = (const float*)d_in[18], *Vb2 = (const float*)d_in[19];
    const float* Vw3 = (const float*)d_in[20], *Vb3 = (const float*)d_in[21];
    const float* Vw4 = (const float*)d_in[22], *Vb4 = (const float*)d_in[23];
    float* out = (float*)d_out;

    // ---- workspace carve-up (~242 MB) ----
    char* p = (char*)d_ws;
    size_t o = 0;
    int*   off  = (int*)(p + o);  o += alignup((size_t)(NC + 1) * 4);
    int*   loff = (int*)(p + o);  o += alignup((size_t)(NL + 1) * 4);
    int*   lcnt = (int*)(p + o);  o += alignup((size_t)NL * 4);
    int*   lcur = (int*)(p + o);  o += alignup((size_t)NL * 4);
    int*   litc = (int*)(p + o);  o += alignup((size_t)NNZE * 4);
    float* L0   = (float*)(p + o); o += alignup((size_t)NL * F * 4);
    float* L1   = (float*)(p + o); o += alignup((size_t)NL * F * 4);
    float* Cb   = (float*)(p + o); o += alignup((size_t)NC * F * 4);
    float* MSG  = (float*)(p + o); o += alignup((size_t)NC * F * 4);
    float* H    = (float*)(p + o); o += alignup((size_t)8400000 * 4);   // 33.6 MB (per-chunk acts)
    float* Psum = (float*)(p + o); o += alignup((size_t)300 * 80 * 4);
    float* Psq  = (float*)(p + o); o += alignup((size_t)300 * 80 * 4);
    float* stats = (float*)(p + o); o += alignup(160 * 4);
    float* lossP = (float*)(p + o); o += alignup(1024 * 4);
    // pre-split weights (bf16 hi/lo, [N][K]) — 192000 elements each of h,l
    unsigned short* Wsp = (unsigned short*)(p + o); o += alignup((size_t)192000 * 2 * 2);
    unsigned short* Cw1h = Wsp,            *Cw1l = Cw1h + 25600;
    unsigned short* Cw2h = Cw1l + 25600,   *Cw2l = Cw2h + 12800;
    unsigned short* Lw1h = Cw2l + 12800,   *Lw1l = Lw1h + 57600;
    unsigned short* Lw2h = Lw1l + 57600,   *Lw2l = Lw2h + 19200;
    unsigned short* Vw1h = Lw2l + 19200,   *Vw1l = Vw1h + 25600;
    unsigned short* Vw2h = Vw1l + 25600,   *Vw2l = Vw2h + 25600;
    unsigned short* Vw3h = Vw2l + 25600,   *Vw3l = Vw3h + 25600;
    (void)ws_size; (void)n_in; (void)in_sizes; (void)out_size;

    // ---- CSR offsets (edge_clause sorted) + lit-CSR ----
    build_off<<<(NNZE + 255) / 256, 256, 0, stream>>>(ec, off, NNZE, NC);
    // NOTE: lcnt and lcur are SEPARATE alignup'd carves — zero each exactly
    // (a single 2*NL zero pass missed the 128-byte pad gap -> poisoned lcur tail).
    zero_int<<<(NL + 255) / 256, 256, 0, stream>>>(lcnt, NL);
    zero_int<<<(NL + 255) / 256, 256, 0, stream>>>(lcur, NL);
    hist_lit<<<(NNZE + 255) / 256, 256, 0, stream>>>(el, lcnt);
    scan_lit<<<1, 256, 0, stream>>>(lcnt, loff);
    scatter_lit<<<(NNZE + 255) / 256, 256, 0, stream>>>(el, ec, loff, lcur, litc);
    seg_sort<<<(NL + 255) / 256, 256, 0, stream>>>(loff, litc);   // deterministic litc

    // ---- weight pre-split ----
    split_w<<<(25600 + 255) / 256, 256, 0, stream>>>(Cw1, 160, 160, Cw1h, Cw1l);
    split_w<<<(12800 + 255) / 256, 256, 0, stream>>>(Cw2, 160,  80, Cw2h, Cw2l);
    split_w<<<(57600 + 255) / 256, 256, 0, stream>>>(Lw1, 240, 240, Lw1h, Lw1l);
    split_w<<<(19200 + 255) / 256, 256, 0, stream>>>(Lw2, 240,  80, Lw2h, Lw2l);
    split_w<<<(25600 + 255) / 256, 256, 0, stream>>>(Vw1, 160, 160, Vw1h, Vw1l);
    split_w<<<(25600 + 255) / 256, 256, 0, stream>>>(Vw2, 160, 160, Vw2h, Vw2l);
    split_w<<<(25600 + 255) / 256, 256, 0, stream>>>(Vw3, 160, 160, Vw3h, Vw3l);

    // ---- init L, C ----
    fill_val<<<(NL * F + 255) / 256, 256, 0, stream>>>(L0, NL * F, l_init);
    fill_val<<<(NC * F + 255) / 256, 256, 0, stream>>>(Cb, NC * F, c_init);

    float* Lc = L0, *Ln = L1;
    const int nblkC = (NC + CS_ROWS - 1) / CS_ROWS;
    const int nblkL = (NL + CS_ROWS - 1) / CS_ROWS;
    const int CCH[5] = {0, 52500, 105000, 157500, 210000};
    const int LCH[4] = {0, 34000, 68000, 100000};

    for (int round = 0; round < 4; ++round) {
        // LC_msgs
        float* LC = MSG;
        lc_gather<<<(NC * 20 + 255) / 256, 256, 0, stream>>>(Lc, el, off, lc_s, LC);

        // C MLP, chunked, in-place on Cb
        for (int ci = 0; ci < 4; ++ci) {
            int r0 = CCH[ci], mloc = CCH[ci + 1] - r0;
            dim3 g1((mloc + TBM - 1) / TBM, 2);
            gemm_mfma<<<g1, 256, 0, stream>>>(Cb + (size_t)r0 * F, LC + (size_t)r0 * F, nullptr,
                                              80, 0, 0, mloc, 160, 160, Cw1h, Cw1l, Cb1, H, 1);
            dim3 g2((mloc + TBM - 1) / TBM, 1);
            gemm_mfma<<<g2, 256, 0, stream>>>(H, nullptr, nullptr,
                                              160, 0, 0, mloc, 160, 80, Cw2h, Cw2l, Cb2, Cb + (size_t)r0 * F, 0);
        }
        colstats_partial<<<nblkC, 256, 0, stream>>>(Cb, NC, Psum, Psq);
        colstats_final<<<80, 256, 0, stream>>>(Psum, Psq, nblkC, NC, stats);
        norm_apply<<<(NC * F + 255) / 256, 256, 0, stream>>>(Cb, NC, stats);

        // CL_msgs via lit-CSR gather (no atomics, no zero pass)
        float* CL = MSG;
        cl_gather<<<(NL * 20 + 255) / 256, 256, 0, stream>>>(Cb, loff, litc, cl_s, CL);

        // L MLP, chunked
        for (int ci = 0; ci < 3; ++ci) {
            int r0 = LCH[ci], mloc = LCH[ci + 1] - r0;
            dim3 g1((mloc + TBM - 1) / TBM, 3);
            gemm_mfma<<<g1, 256, 0, stream>>>(Lc + (size_t)r0 * F, CL + (size_t)r0 * F, Lc,
                                              80, 1, r0, mloc, 240, 240, Lw1h, Lw1l, Lb1, H, 1);
            dim3 g2((mloc + TBM - 1) / TBM, 1);
            gemm_mfma<<<g2, 256, 0, stream>>>(H, nullptr, nullptr,
                                              240, 0, 0, mloc, 240, 80, Lw2h, Lw2l, Lb2, Ln + (size_t)r0 * F, 0);
        }
        colstats_partial<<<nblkL, 256, 0, stream>>>(Ln, NL, Psum, Psq);
        colstats_final<<<80, 256, 0, stream>>>(Psum, Psq, nblkL, NL, stats);
        norm_apply<<<(NL * F + 255) / 256, 256, 0, stream>>>(Ln, NL, stats);

        float* t = Lc; Lc = Ln; Ln = t;
    }

    // ---- V MLP ----
    {
        float* H2 = MSG;
        dim3 g((NV + TBM - 1) / TBM, 2);
        gemm_mfma<<<g, 256, 0, stream>>>(Lc, Lc + (size_t)NV * F, nullptr,
                                         80, 0, 0, NV, 160, 160, Vw1h, Vw1l, Vb1, H, 1);
        gemm_mfma<<<g, 256, 0, stream>>>(H, nullptr, nullptr,
                                         160, 0, 0, NV, 160, 160, Vw2h, Vw2l, Vb2, H2, 1);
        gemm_mfma<<<g, 256, 0, stream>>>(H2, nullptr, nullptr,
                                         160, 0, 0, NV, 160, 160, Vw3h, Vw3l, Vb3, H, 1);
        vscore_kernel<<<(NV * 64 + 255) / 256, 256, 0, stream>>>(H, Vw4, Vb4, out, NV);
    }

    // ---- loss ----
    {
        int nblk = (NC + 255) / 256;
        loss_clause<<<nblk, 256, 0, stream>>>(el, off, out, lossP, NC);
        loss_final<<<1, 256, 0, stream>>>(lossP, nblk, out + NV);
    }
}